// Round 1
// baseline (3275.936 us; speedup 1.0000x reference)
//
#include <hip/hip_runtime.h>

#define NFEAT 128
#define GEMM_ROWS 16

// ---------------- degree ----------------
__global__ void deg_init_kernel(float* __restrict__ deg, int n) {
    int i = blockIdx.x * blockDim.x + threadIdx.x;
    if (i < n) deg[i] = 1.0f;  // self loop
}

__global__ void deg_acc_kernel(const int* __restrict__ row, float* __restrict__ deg, int E) {
    int e = blockIdx.x * blockDim.x + threadIdx.x;
    if (e < E) atomicAdd(&deg[row[e]], 1.0f);
}

// ---------------- linear: x = feat @ W^T + b ----------------
__launch_bounds__(256)
__global__ void gemm_kernel(const float* __restrict__ feat, const float* __restrict__ W,
                            const float* __restrict__ b, float* __restrict__ x, int n) {
    __shared__ float WT[128][128];        // WT[k][c] = W[c][k]; reads at [k][lane] are conflict-free
    __shared__ float F[GEMM_ROWS][128];   // feature tile; reads are wave-uniform broadcasts

    int t = threadIdx.x;

    // Load W (128x128, row-major [out][in]) transposed into LDS.
    {
        int c = t >> 1;                 // output channel
        int kbase = (t & 1) * 64;       // half of the k range
        const float4* Wrow = (const float4*)(W + c * 128 + kbase);
#pragma unroll
        for (int i = 0; i < 16; ++i) {
            float4 w4 = Wrow[i];
            int k = kbase + i * 4;
            WT[k + 0][c] = w4.x;
            WT[k + 1][c] = w4.y;
            WT[k + 2][c] = w4.z;
            WT[k + 3][c] = w4.w;
        }
    }

    int row0 = blockIdx.x * GEMM_ROWS;

    // Load feature tile (16 rows x 128), coalesced.
    {
        int r = t >> 4;
        int cb = (t & 15) * 8;
        int gr = row0 + r;
        float4 a = make_float4(0.f, 0.f, 0.f, 0.f);
        float4 d = a;
        if (gr < n) {
            const float4* src = (const float4*)(feat + (size_t)gr * 128 + cb);
            a = src[0];
            d = src[1];
        }
        *(float4*)&F[r][cb] = a;
        *(float4*)&F[r][cb + 4] = d;
    }

    __syncthreads();

    int col = t & 127;   // output channel for this thread
    int rh = t >> 7;     // 0 or 1: which 8-row half (wave-uniform)
    float bb = b[col];
    float acc[8];
#pragma unroll
    for (int r = 0; r < 8; ++r) acc[r] = bb;

#pragma unroll
    for (int k = 0; k < 128; k += 4) {
        float w0 = WT[k + 0][col];
        float w1 = WT[k + 1][col];
        float w2 = WT[k + 2][col];
        float w3 = WT[k + 3][col];
#pragma unroll
        for (int r = 0; r < 8; ++r) {
            float4 f4 = *(const float4*)&F[rh * 8 + r][k];
            acc[r] = fmaf(f4.x, w0, acc[r]);
            acc[r] = fmaf(f4.y, w1, acc[r]);
            acc[r] = fmaf(f4.z, w2, acc[r]);
            acc[r] = fmaf(f4.w, w3, acc[r]);
        }
    }

#pragma unroll
    for (int r = 0; r < 8; ++r) {
        int gr = row0 + rh * 8 + r;
        if (gr < n) x[(size_t)gr * 128 + col] = acc[r];
    }
}

// ---------------- self-loop init + dis = rsqrt(deg) ----------------
__global__ void selfloop_kernel(const float* __restrict__ x, const float* __restrict__ deg,
                                float* __restrict__ out, float* __restrict__ dis, int n) {
    int t = blockIdx.x * blockDim.x + threadIdx.x;  // one per float4; n*32 total
    if (t >= n * 32) return;
    int node = t >> 5;
    float d = deg[node];
    float inv = 1.0f / d;  // self-loop norm = dis^2 = 1/deg
    float4 xv = ((const float4*)x)[t];
    float4 o = make_float4(xv.x * inv, xv.y * inv, xv.z * inv, xv.w * inv);
    ((float4*)out)[t] = o;
    if ((t & 31) == 0) dis[node] = rsqrtf(d);
}

// ---------------- edge scatter: out[col] += dis[row]*dis[col] * x[row] ----------------
__global__ void scatter_kernel(const int* __restrict__ row, const int* __restrict__ col,
                               const float* __restrict__ x, const float* __restrict__ dis,
                               float* __restrict__ out, int E) {
    long long t = (long long)blockIdx.x * blockDim.x + threadIdx.x;
    int e = (int)(t >> 6);
    if (e >= E) return;
    int lane = (int)(t & 63);
    int r = row[e];
    int c = col[e];
    float norm = dis[r] * dis[c];
    float2 xv = ((const float2*)x)[(size_t)r * 64 + lane];
    atomicAdd(&out[(size_t)c * 128 + lane * 2 + 0], xv.x * norm);
    atomicAdd(&out[(size_t)c * 128 + lane * 2 + 1], xv.y * norm);
}

extern "C" void kernel_launch(void* const* d_in, const int* in_sizes, int n_in,
                              void* d_out, int out_size, void* d_ws, size_t ws_size,
                              hipStream_t stream) {
    const float* feat = (const float*)d_in[0];
    const int*   edges = (const int*)d_in[1];
    const float* W = (const float*)d_in[2];
    const float* b = (const float*)d_in[3];
    float* out = (float*)d_out;

    int n = in_sizes[0] / NFEAT;   // 100000
    int E = in_sizes[1] / 2;       // 1600000
    const int* row = edges;        // edges[0] = source
    const int* col = edges + E;    // edges[1] = target

    // workspace layout: x [n*128] | deg [n] | dis [n]
    float* x   = (float*)d_ws;
    float* deg = x + (size_t)n * NFEAT;
    float* dis = deg + n;

    // 1) degree
    deg_init_kernel<<<(n + 255) / 256, 256, 0, stream>>>(deg, n);
    deg_acc_kernel<<<(E + 255) / 256, 256, 0, stream>>>(row, deg, E);

    // 2) linear transform
    gemm_kernel<<<(n + GEMM_ROWS - 1) / GEMM_ROWS, 256, 0, stream>>>(feat, W, b, x, n);

    // 3) self-loop contribution initializes out; also writes dis
    selfloop_kernel<<<(n * 32 + 255) / 256, 256, 0, stream>>>(x, deg, out, dis, n);

    // 4) edge scatter, one wave per edge
    long long threads = (long long)E * 64;
    int blocks = (int)((threads + 255) / 256);
    scatter_kernel<<<blocks, 256, 0, stream>>>(row, col, x, dis, out, E);
}

// Round 2
// 1543.047 us; speedup vs baseline: 2.1230x; 2.1230x over previous
//
#include <hip/hip_runtime.h>

#define NFEAT 128
#define ROWS 32

// ---------------- degree ----------------
__global__ void deg_init_kernel(float* __restrict__ deg, int n) {
    int i = blockIdx.x * blockDim.x + threadIdx.x;
    if (i < n) deg[i] = 1.0f;  // self loop
}

__global__ void deg_acc_kernel(const int* __restrict__ row, float* __restrict__ deg, int E) {
    int e = blockIdx.x * blockDim.x + threadIdx.x;
    if (e < E) atomicAdd(&deg[row[e]], 1.0f);
}

// ---------------- linear: x = feat @ W^T + b ----------------
// Block: 256 threads, 32 rows. K split into two 64-halves so LDS = 32KB (WT) + ~8.5KB (F)
// -> 3 blocks/CU. Thread tile: 4 rows x 4 cols, 16 fp32 accumulators.
__launch_bounds__(256, 3)
__global__ void gemm_kernel(const float* __restrict__ feat, const float* __restrict__ W,
                            const float* __restrict__ b, float* __restrict__ x, int n) {
    __shared__ float WT[64][128];   // WT[k][c] for current K-half (32 KB)
    __shared__ float F[ROWS][68];   // padded feature tile (~8.7 KB)

    const int t = threadIdx.x;
    const int row0 = blockIdx.x * ROWS;
    const int cg = t & 31;          // col group -> cols c0..c0+3
    const int rg = t >> 5;          // row group -> rows r0..r0+3
    const int c0 = cg * 4;
    const int r0 = rg * 4;

    float4 bb = *(const float4*)(b + c0);
    float4 acc0 = bb, acc1 = bb, acc2 = bb, acc3 = bb;

    for (int kh = 0; kh < 2; ++kh) {
        // stage W-half transposed: thread covers one output channel c, 32 k's
        {
            int c = t >> 1;
            int kb = (t & 1) * 32;
            const float4* src = (const float4*)(W + (size_t)c * NFEAT + kh * 64 + kb);
#pragma unroll
            for (int i = 0; i < 8; ++i) {
                float4 w4 = src[i];
                int k = kb + i * 4;
                WT[k + 0][c] = w4.x;
                WT[k + 1][c] = w4.y;
                WT[k + 2][c] = w4.z;
                WT[k + 3][c] = w4.w;
            }
        }
        // stage feature tile half: thread covers row r, 8 k's
        {
            int r = t >> 3;
            int kb = (t & 7) * 8;
            int gr = row0 + r;
            float4 a = make_float4(0.f, 0.f, 0.f, 0.f);
            float4 d = a;
            if (gr < n) {
                const float4* src = (const float4*)(feat + (size_t)gr * NFEAT + kh * 64 + kb);
                a = src[0];
                d = src[1];
            }
            *(float4*)&F[r][kb] = a;
            *(float4*)&F[r][kb + 4] = d;
        }
        __syncthreads();

#pragma unroll 2
        for (int k = 0; k < 64; k += 4) {
            float4 w0 = *(const float4*)&WT[k + 0][c0];
            float4 w1 = *(const float4*)&WT[k + 1][c0];
            float4 w2 = *(const float4*)&WT[k + 2][c0];
            float4 w3 = *(const float4*)&WT[k + 3][c0];

            float4 f0 = *(const float4*)&F[r0 + 0][k];
            float4 f1 = *(const float4*)&F[r0 + 1][k];
            float4 f2 = *(const float4*)&F[r0 + 2][k];
            float4 f3 = *(const float4*)&F[r0 + 3][k];

            acc0.x = fmaf(f0.x, w0.x, acc0.x); acc0.y = fmaf(f0.x, w0.y, acc0.y);
            acc0.z = fmaf(f0.x, w0.z, acc0.z); acc0.w = fmaf(f0.x, w0.w, acc0.w);
            acc0.x = fmaf(f0.y, w1.x, acc0.x); acc0.y = fmaf(f0.y, w1.y, acc0.y);
            acc0.z = fmaf(f0.y, w1.z, acc0.z); acc0.w = fmaf(f0.y, w1.w, acc0.w);
            acc0.x = fmaf(f0.z, w2.x, acc0.x); acc0.y = fmaf(f0.z, w2.y, acc0.y);
            acc0.z = fmaf(f0.z, w2.z, acc0.z); acc0.w = fmaf(f0.z, w2.w, acc0.w);
            acc0.x = fmaf(f0.w, w3.x, acc0.x); acc0.y = fmaf(f0.w, w3.y, acc0.y);
            acc0.z = fmaf(f0.w, w3.z, acc0.z); acc0.w = fmaf(f0.w, w3.w, acc0.w);

            acc1.x = fmaf(f1.x, w0.x, acc1.x); acc1.y = fmaf(f1.x, w0.y, acc1.y);
            acc1.z = fmaf(f1.x, w0.z, acc1.z); acc1.w = fmaf(f1.x, w0.w, acc1.w);
            acc1.x = fmaf(f1.y, w1.x, acc1.x); acc1.y = fmaf(f1.y, w1.y, acc1.y);
            acc1.z = fmaf(f1.y, w1.z, acc1.z); acc1.w = fmaf(f1.y, w1.w, acc1.w);
            acc1.x = fmaf(f1.z, w2.x, acc1.x); acc1.y = fmaf(f1.z, w2.y, acc1.y);
            acc1.z = fmaf(f1.z, w2.z, acc1.z); acc1.w = fmaf(f1.z, w2.w, acc1.w);
            acc1.x = fmaf(f1.w, w3.x, acc1.x); acc1.y = fmaf(f1.w, w3.y, acc1.y);
            acc1.z = fmaf(f1.w, w3.z, acc1.z); acc1.w = fmaf(f1.w, w3.w, acc1.w);

            acc2.x = fmaf(f2.x, w0.x, acc2.x); acc2.y = fmaf(f2.x, w0.y, acc2.y);
            acc2.z = fmaf(f2.x, w0.z, acc2.z); acc2.w = fmaf(f2.x, w0.w, acc2.w);
            acc2.x = fmaf(f2.y, w1.x, acc2.x); acc2.y = fmaf(f2.y, w1.y, acc2.y);
            acc2.z = fmaf(f2.y, w1.z, acc2.z); acc2.w = fmaf(f2.y, w1.w, acc2.w);
            acc2.x = fmaf(f2.z, w2.x, acc2.x); acc2.y = fmaf(f2.z, w2.y, acc2.y);
            acc2.z = fmaf(f2.z, w2.z, acc2.z); acc2.w = fmaf(f2.z, w2.w, acc2.w);
            acc2.x = fmaf(f2.w, w3.x, acc2.x); acc2.y = fmaf(f2.w, w3.y, acc2.y);
            acc2.z = fmaf(f2.w, w3.z, acc2.z); acc2.w = fmaf(f2.w, w3.w, acc2.w);

            acc3.x = fmaf(f3.x, w0.x, acc3.x); acc3.y = fmaf(f3.x, w0.y, acc3.y);
            acc3.z = fmaf(f3.x, w0.z, acc3.z); acc3.w = fmaf(f3.x, w0.w, acc3.w);
            acc3.x = fmaf(f3.y, w1.x, acc3.x); acc3.y = fmaf(f3.y, w1.y, acc3.y);
            acc3.z = fmaf(f3.y, w1.z, acc3.z); acc3.w = fmaf(f3.y, w1.w, acc3.w);
            acc3.x = fmaf(f3.z, w2.x, acc3.x); acc3.y = fmaf(f3.z, w2.y, acc3.y);
            acc3.z = fmaf(f3.z, w2.z, acc3.z); acc3.w = fmaf(f3.z, w2.w, acc3.w);
            acc3.x = fmaf(f3.w, w3.x, acc3.x); acc3.y = fmaf(f3.w, w3.y, acc3.y);
            acc3.z = fmaf(f3.w, w3.z, acc3.z); acc3.w = fmaf(f3.w, w3.w, acc3.w);
        }
        __syncthreads();
    }

    int gr = row0 + r0;
    if (gr + 0 < n) *(float4*)(x + (size_t)(gr + 0) * NFEAT + c0) = acc0;
    if (gr + 1 < n) *(float4*)(x + (size_t)(gr + 1) * NFEAT + c0) = acc1;
    if (gr + 2 < n) *(float4*)(x + (size_t)(gr + 2) * NFEAT + c0) = acc2;
    if (gr + 3 < n) *(float4*)(x + (size_t)(gr + 3) * NFEAT + c0) = acc3;
}

// ---------------- self-loop init + dis = rsqrt(deg) ----------------
__global__ void selfloop_kernel(const float* __restrict__ x, const float* __restrict__ deg,
                                float* __restrict__ out, float* __restrict__ dis, int n) {
    int t = blockIdx.x * blockDim.x + threadIdx.x;  // one per float4; n*32 total
    if (t >= n * 32) return;
    int node = t >> 5;
    float d = deg[node];
    float inv = 1.0f / d;  // self-loop norm = dis^2 = 1/deg
    float4 xv = ((const float4*)x)[t];
    float4 o = make_float4(xv.x * inv, xv.y * inv, xv.z * inv, xv.w * inv);
    ((float4*)out)[t] = o;
    if ((t & 31) == 0) dis[node] = rsqrtf(d);
}

// ---------------- edge scatter: out[col] += dis[row]*dis[col] * x[row] ----------------
__global__ void scatter_kernel(const int* __restrict__ row, const int* __restrict__ col,
                               const float* __restrict__ x, const float* __restrict__ dis,
                               float* __restrict__ out, int E) {
    long long t = (long long)blockIdx.x * blockDim.x + threadIdx.x;
    int e = (int)(t >> 6);
    if (e >= E) return;
    int lane = (int)(t & 63);
    int r = row[e];
    int c = col[e];
    float norm = dis[r] * dis[c];
    float2 xv = ((const float2*)x)[(size_t)r * 64 + lane];
    atomicAdd(&out[(size_t)c * 128 + lane * 2 + 0], xv.x * norm);
    atomicAdd(&out[(size_t)c * 128 + lane * 2 + 1], xv.y * norm);
}

extern "C" void kernel_launch(void* const* d_in, const int* in_sizes, int n_in,
                              void* d_out, int out_size, void* d_ws, size_t ws_size,
                              hipStream_t stream) {
    const float* feat = (const float*)d_in[0];
    const int*   edges = (const int*)d_in[1];
    const float* W = (const float*)d_in[2];
    const float* b = (const float*)d_in[3];
    float* out = (float*)d_out;

    int n = in_sizes[0] / NFEAT;   // 100000
    int E = in_sizes[1] / 2;       // 1600000
    const int* row = edges;        // edges[0] = source
    const int* col = edges + E;    // edges[1] = target

    // workspace layout: x [n*128] | deg [n] | dis [n]
    float* x   = (float*)d_ws;
    float* deg = x + (size_t)n * NFEAT;
    float* dis = deg + n;

    // 1) degree
    deg_init_kernel<<<(n + 255) / 256, 256, 0, stream>>>(deg, n);
    deg_acc_kernel<<<(E + 255) / 256, 256, 0, stream>>>(row, deg, E);

    // 2) linear transform
    gemm_kernel<<<(n + ROWS - 1) / ROWS, 256, 0, stream>>>(feat, W, b, x, n);

    // 3) self-loop contribution initializes out; also writes dis
    selfloop_kernel<<<(n * 32 + 255) / 256, 256, 0, stream>>>(x, deg, out, dis, n);

    // 4) edge scatter, one wave per edge
    long long threads = (long long)E * 64;
    int blocks = (int)((threads + 255) / 256);
    scatter_kernel<<<blocks, 256, 0, stream>>>(row, col, x, dis, out, E);
}

// Round 3
// 552.197 us; speedup vs baseline: 5.9326x; 2.7944x over previous
//
#include <hip/hip_runtime.h>

#define NFEAT 128

// ---------------- init: deg=1 (self loop), cnt=0 ----------------
__global__ void init_kernel(float* __restrict__ deg, int* __restrict__ cnt, int n) {
    int i = blockIdx.x * blockDim.x + threadIdx.x;
    if (i < n) { deg[i] = 1.0f; cnt[i] = 0; }
}

// ---------------- histograms: deg over row (source), cnt over col (target) ----------------
__global__ void hist_kernel(const int* __restrict__ row, const int* __restrict__ col,
                            float* __restrict__ deg, int* __restrict__ cnt, int E) {
    int e = blockIdx.x * blockDim.x + threadIdx.x;
    if (e < E) {
        atomicAdd(&deg[row[e]], 1.0f);
        atomicAdd(&cnt[col[e]], 1);
    }
}

__global__ void dis_kernel(const float* __restrict__ deg, float* __restrict__ dis, int n) {
    int i = blockIdx.x * blockDim.x + threadIdx.x;
    if (i < n) dis[i] = rsqrtf(deg[i]);
}

// ---------------- hierarchical exclusive scan of cnt (1024 elems / block) ----------------
__global__ void scan_bsum_kernel(const int* __restrict__ cnt, int* __restrict__ bsum, int n) {
    __shared__ int s[256];
    int base = blockIdx.x * 1024;
    int t = threadIdx.x;
    int v = 0;
#pragma unroll
    for (int i = 0; i < 4; ++i) {
        int idx = base + t * 4 + i;
        if (idx < n) v += cnt[idx];
    }
    s[t] = v;
    __syncthreads();
    for (int o = 128; o > 0; o >>= 1) {
        if (t < o) s[t] += s[t + o];
        __syncthreads();
    }
    if (t == 0) bsum[blockIdx.x] = s[0];
}

__global__ void scan_top_kernel(int* __restrict__ bsum, int nb) {
    __shared__ int s[256];
    int t = threadIdx.x;
    int v = (t < nb) ? bsum[t] : 0;
    s[t] = v;
    __syncthreads();
    for (int o = 1; o < 256; o <<= 1) {
        int add = (t >= o) ? s[t - o] : 0;
        __syncthreads();
        s[t] += add;
        __syncthreads();
    }
    if (t < nb) bsum[t] = s[t] - v;  // exclusive
}

__global__ void scan_write_kernel(const int* __restrict__ cnt, const int* __restrict__ bsum,
                                  int* __restrict__ off, int* __restrict__ cur, int n) {
    __shared__ int s[256];
    int base = blockIdx.x * 1024;
    int t = threadIdx.x;
    int v[4];
    int sum = 0;
#pragma unroll
    for (int i = 0; i < 4; ++i) {
        int idx = base + t * 4 + i;
        v[i] = (idx < n) ? cnt[idx] : 0;
        sum += v[i];
    }
    s[t] = sum;
    __syncthreads();
    for (int o = 1; o < 256; o <<= 1) {
        int add = (t >= o) ? s[t - o] : 0;
        __syncthreads();
        s[t] += add;
        __syncthreads();
    }
    int p = bsum[blockIdx.x] + s[t] - sum;  // exclusive prefix for this thread's 4 elems
#pragma unroll
    for (int i = 0; i < 4; ++i) {
        int idx = base + t * 4 + i;
        if (idx < n) { off[idx] = p; cur[idx] = p; p += v[i]; }
    }
}

// ---------------- bucket fill: rows grouped by target ----------------
__global__ void fill_kernel(const int* __restrict__ row, const int* __restrict__ col,
                            int* __restrict__ cur, int* __restrict__ rows_buf, int E) {
    int e = blockIdx.x * blockDim.x + threadIdx.x;
    if (e < E) {
        int p = atomicAdd(&cur[col[e]], 1);
        rows_buf[p] = row[e];
    }
}

// ---------------- linear: x = feat @ W^T + b (unchanged from R1) ----------------
__launch_bounds__(256, 3)
__global__ void gemm_kernel(const float* __restrict__ feat, const float* __restrict__ W,
                            const float* __restrict__ b, float* __restrict__ x, int n) {
    __shared__ float WT[64][128];
    __shared__ float F[32][68];

    const int t = threadIdx.x;
    const int row0 = blockIdx.x * 32;
    const int c0 = (t & 31) * 4;
    const int r0 = (t >> 5) * 4;

    float4 bb = *(const float4*)(b + c0);
    float4 acc0 = bb, acc1 = bb, acc2 = bb, acc3 = bb;

    for (int kh = 0; kh < 2; ++kh) {
        {
            int c = t >> 1;
            int kb = (t & 1) * 32;
            const float4* src = (const float4*)(W + (size_t)c * NFEAT + kh * 64 + kb);
#pragma unroll
            for (int i = 0; i < 8; ++i) {
                float4 w4 = src[i];
                int k = kb + i * 4;
                WT[k + 0][c] = w4.x;
                WT[k + 1][c] = w4.y;
                WT[k + 2][c] = w4.z;
                WT[k + 3][c] = w4.w;
            }
        }
        {
            int r = t >> 3;
            int kb = (t & 7) * 8;
            int gr = row0 + r;
            float4 a = make_float4(0.f, 0.f, 0.f, 0.f);
            float4 d = a;
            if (gr < n) {
                const float4* src = (const float4*)(feat + (size_t)gr * NFEAT + kh * 64 + kb);
                a = src[0];
                d = src[1];
            }
            *(float4*)&F[r][kb] = a;
            *(float4*)&F[r][kb + 4] = d;
        }
        __syncthreads();

#pragma unroll 2
        for (int k = 0; k < 64; k += 4) {
            float4 w0 = *(const float4*)&WT[k + 0][c0];
            float4 w1 = *(const float4*)&WT[k + 1][c0];
            float4 w2 = *(const float4*)&WT[k + 2][c0];
            float4 w3 = *(const float4*)&WT[k + 3][c0];

            float4 f0 = *(const float4*)&F[r0 + 0][k];
            float4 f1 = *(const float4*)&F[r0 + 1][k];
            float4 f2 = *(const float4*)&F[r0 + 2][k];
            float4 f3 = *(const float4*)&F[r0 + 3][k];

            acc0.x = fmaf(f0.x, w0.x, acc0.x); acc0.y = fmaf(f0.x, w0.y, acc0.y);
            acc0.z = fmaf(f0.x, w0.z, acc0.z); acc0.w = fmaf(f0.x, w0.w, acc0.w);
            acc0.x = fmaf(f0.y, w1.x, acc0.x); acc0.y = fmaf(f0.y, w1.y, acc0.y);
            acc0.z = fmaf(f0.y, w1.z, acc0.z); acc0.w = fmaf(f0.y, w1.w, acc0.w);
            acc0.x = fmaf(f0.z, w2.x, acc0.x); acc0.y = fmaf(f0.z, w2.y, acc0.y);
            acc0.z = fmaf(f0.z, w2.z, acc0.z); acc0.w = fmaf(f0.z, w2.w, acc0.w);
            acc0.x = fmaf(f0.w, w3.x, acc0.x); acc0.y = fmaf(f0.w, w3.y, acc0.y);
            acc0.z = fmaf(f0.w, w3.z, acc0.z); acc0.w = fmaf(f0.w, w3.w, acc0.w);

            acc1.x = fmaf(f1.x, w0.x, acc1.x); acc1.y = fmaf(f1.x, w0.y, acc1.y);
            acc1.z = fmaf(f1.x, w0.z, acc1.z); acc1.w = fmaf(f1.x, w0.w, acc1.w);
            acc1.x = fmaf(f1.y, w1.x, acc1.x); acc1.y = fmaf(f1.y, w1.y, acc1.y);
            acc1.z = fmaf(f1.y, w1.z, acc1.z); acc1.w = fmaf(f1.y, w1.w, acc1.w);
            acc1.x = fmaf(f1.z, w2.x, acc1.x); acc1.y = fmaf(f1.z, w2.y, acc1.y);
            acc1.z = fmaf(f1.z, w2.z, acc1.z); acc1.w = fmaf(f1.z, w2.w, acc1.w);
            acc1.x = fmaf(f1.w, w3.x, acc1.x); acc1.y = fmaf(f1.w, w3.y, acc1.y);
            acc1.z = fmaf(f1.w, w3.z, acc1.z); acc1.w = fmaf(f1.w, w3.w, acc1.w);

            acc2.x = fmaf(f2.x, w0.x, acc2.x); acc2.y = fmaf(f2.x, w0.y, acc2.y);
            acc2.z = fmaf(f2.x, w0.z, acc2.z); acc2.w = fmaf(f2.x, w0.w, acc2.w);
            acc2.x = fmaf(f2.y, w1.x, acc2.x); acc2.y = fmaf(f2.y, w1.y, acc2.y);
            acc2.z = fmaf(f2.y, w1.z, acc2.z); acc2.w = fmaf(f2.y, w1.w, acc2.w);
            acc2.x = fmaf(f2.z, w2.x, acc2.x); acc2.y = fmaf(f2.z, w2.y, acc2.y);
            acc2.z = fmaf(f2.z, w2.z, acc2.z); acc2.w = fmaf(f2.z, w2.w, acc2.w);
            acc2.x = fmaf(f2.w, w3.x, acc2.x); acc2.y = fmaf(f2.w, w3.y, acc2.y);
            acc2.z = fmaf(f2.w, w3.z, acc2.z); acc2.w = fmaf(f2.w, w3.w, acc2.w);

            acc3.x = fmaf(f3.x, w0.x, acc3.x); acc3.y = fmaf(f3.x, w0.y, acc3.y);
            acc3.z = fmaf(f3.x, w0.z, acc3.z); acc3.w = fmaf(f3.x, w0.w, acc3.w);
            acc3.x = fmaf(f3.y, w1.x, acc3.x); acc3.y = fmaf(f3.y, w1.y, acc3.y);
            acc3.z = fmaf(f3.y, w1.z, acc3.z); acc3.w = fmaf(f3.y, w1.w, acc3.w);
            acc3.x = fmaf(f3.z, w2.x, acc3.x); acc3.y = fmaf(f3.z, w2.y, acc3.y);
            acc3.z = fmaf(f3.z, w2.z, acc3.z); acc3.w = fmaf(f3.z, w2.w, acc3.w);
            acc3.x = fmaf(f3.w, w3.x, acc3.x); acc3.y = fmaf(f3.w, w3.y, acc3.y);
            acc3.z = fmaf(f3.w, w3.z, acc3.z); acc3.w = fmaf(f3.w, w3.w, acc3.w);
        }
        __syncthreads();
    }

    int gr = row0 + r0;
    if (gr + 0 < n) *(float4*)(x + (size_t)(gr + 0) * NFEAT + c0) = acc0;
    if (gr + 1 < n) *(float4*)(x + (size_t)(gr + 1) * NFEAT + c0) = acc1;
    if (gr + 2 < n) *(float4*)(x + (size_t)(gr + 2) * NFEAT + c0) = acc2;
    if (gr + 3 < n) *(float4*)(x + (size_t)(gr + 3) * NFEAT + c0) = acc3;
}

// ---------------- gather: out[c] = dis[c]^2 * x[c] + sum_{r->c} dis[r]*dis[c]*x[r] ----------------
// One wave per target node; 4 nodes per 256-thread block.
__launch_bounds__(256)
__global__ void gather_kernel(const int* __restrict__ rows_buf, const int* __restrict__ off,
                              const int* __restrict__ cnt, const float* __restrict__ x,
                              const float* __restrict__ dis, float* __restrict__ out, int n) {
    int w = threadIdx.x >> 6;
    int lane = threadIdx.x & 63;
    int c = blockIdx.x * 4 + w;
    if (c >= n) return;

    float disc = dis[c];
    int start = off[c];
    int len = cnt[c];
    const float2* x2 = (const float2*)x;

    float2 acc;
    {
        float2 xv = x2[(size_t)c * 64 + lane];
        float sl = disc * disc;  // self-loop norm = 1/deg
        acc.x = xv.x * sl;
        acc.y = xv.y * sl;
    }

    int j = 0;
    for (; j + 1 < len; j += 2) {
        int r0 = rows_buf[start + j];
        int r1 = rows_buf[start + j + 1];
        float n0 = dis[r0] * disc;
        float n1 = dis[r1] * disc;
        float2 a = x2[(size_t)r0 * 64 + lane];
        float2 b = x2[(size_t)r1 * 64 + lane];
        acc.x = fmaf(a.x, n0, acc.x); acc.y = fmaf(a.y, n0, acc.y);
        acc.x = fmaf(b.x, n1, acc.x); acc.y = fmaf(b.y, n1, acc.y);
    }
    if (j < len) {
        int r = rows_buf[start + j];
        float nn = dis[r] * disc;
        float2 a = x2[(size_t)r * 64 + lane];
        acc.x = fmaf(a.x, nn, acc.x); acc.y = fmaf(a.y, nn, acc.y);
    }

    ((float2*)out)[(size_t)c * 64 + lane] = acc;
}

extern "C" void kernel_launch(void* const* d_in, const int* in_sizes, int n_in,
                              void* d_out, int out_size, void* d_ws, size_t ws_size,
                              hipStream_t stream) {
    const float* feat = (const float*)d_in[0];
    const int*   edges = (const int*)d_in[1];
    const float* W = (const float*)d_in[2];
    const float* b = (const float*)d_in[3];
    float* out = (float*)d_out;

    int n = in_sizes[0] / NFEAT;   // 100000
    int E = in_sizes[1] / 2;       // 1600000
    const int* row = edges;        // edges[0] = source
    const int* col = edges + E;    // edges[1] = target

    // workspace layout
    float* x    = (float*)d_ws;                       // n*128 f
    float* deg  = x + (size_t)n * NFEAT;              // n f
    float* dis  = deg + n;                            // n f
    int*   cnt  = (int*)(dis + n);                    // n i
    int*   off  = cnt + n;                            // n i
    int*   cur  = off + n;                            // n i
    int*   rows_buf = cur + n;                        // E i
    int*   bsum = rows_buf + E;                       // ~128 i

    int nb = (n + 1023) / 1024;   // 98 scan blocks

    // 1) init + histograms + dis
    init_kernel<<<(n + 255) / 256, 256, 0, stream>>>(deg, cnt, n);
    hist_kernel<<<(E + 255) / 256, 256, 0, stream>>>(row, col, deg, cnt, E);
    dis_kernel<<<(n + 255) / 256, 256, 0, stream>>>(deg, dis, n);

    // 2) exclusive scan of cnt -> off, cur
    scan_bsum_kernel<<<nb, 256, 0, stream>>>(cnt, bsum, n);
    scan_top_kernel<<<1, 256, 0, stream>>>(bsum, nb);
    scan_write_kernel<<<nb, 256, 0, stream>>>(cnt, bsum, off, cur, n);

    // 3) bucket fill (counting sort of edges by target)
    fill_kernel<<<(E + 255) / 256, 256, 0, stream>>>(row, col, cur, rows_buf, E);

    // 4) linear transform (overlaps nothing but independent of CSR kernels)
    gemm_kernel<<<(n + 31) / 32, 256, 0, stream>>>(feat, W, b, x, n);

    // 5) atomic-free gather (fuses self-loop)
    gather_kernel<<<(n + 3) / 4, 256, 0, stream>>>(rows_buf, off, cnt, x, dis, out, n);
}

// Round 4
// 501.297 us; speedup vs baseline: 6.5349x; 1.1015x over previous
//
#include <hip/hip_runtime.h>

#define NFEAT 128
#define EPB 131072      // edges per histogram block (2^17)
#define LOG_EPB 17
#define CH 12800        // nodes per chunk (LDS ints)
#define NCHUNK 8        // 8*12800 = 102400 >= 100000

// ---------------- LDS-privatized partial histograms ----------------
// grid: (NB, NCHUNK, 2). z=0: rows -> ph_row. z=1: cols -> ph_col + rank[e].
__global__ void hist_part_kernel(const int* __restrict__ rows, const int* __restrict__ cols,
                                 int* __restrict__ ph_row, int* __restrict__ ph_col,
                                 int* __restrict__ rank, int E, int n) {
    __shared__ int h[CH];
    const int b = blockIdx.x;
    const int c0 = blockIdx.y * CH;
    const int z = blockIdx.z;
    const int* keys = z ? cols : rows;
    int* ph = z ? ph_col : ph_row;

    for (int i = threadIdx.x; i < CH; i += 256) h[i] = 0;
    __syncthreads();

    int lo = b * EPB;
    int hi = min(E, lo + EPB);
    if (z) {
        for (int e = lo + threadIdx.x; e < hi; e += 256) {
            int k = keys[e] - c0;
            if ((unsigned)k < CH) rank[e] = atomicAdd(&h[k], 1);
        }
    } else {
        for (int e = lo + threadIdx.x; e < hi; e += 256) {
            int k = keys[e] - c0;
            if ((unsigned)k < CH) atomicAdd(&h[k], 1);
        }
    }
    __syncthreads();

    for (int i = threadIdx.x; i < CH; i += 256) {
        int k = c0 + i;
        if (k < n) ph[(size_t)b * n + k] = h[i];
    }
}

// ---------------- per-key: row-sum -> dis; col exclusive-cum over blocks -> colcnt ----------------
__global__ void cum_kernel(const int* __restrict__ ph_row, int* __restrict__ ph_col,
                           float* __restrict__ dis, int* __restrict__ colcnt, int NB, int n) {
    int k = blockIdx.x * 256 + threadIdx.x;
    if (k >= n) return;
    int rs = 0;
    for (int b = 0; b < NB; ++b) rs += ph_row[(size_t)b * n + k];
    dis[k] = rsqrtf(1.0f + (float)rs);
    int acc = 0;
    for (int b = 0; b < NB; ++b) {
        int v = ph_col[(size_t)b * n + k];
        ph_col[(size_t)b * n + k] = acc;
        acc += v;
    }
    colcnt[k] = acc;
}

// ---------------- hierarchical exclusive scan of colcnt -> off ----------------
__global__ void scan_bsum_kernel(const int* __restrict__ cnt, int* __restrict__ bsum, int n) {
    __shared__ int s[256];
    int base = blockIdx.x * 1024;
    int t = threadIdx.x;
    int v = 0;
#pragma unroll
    for (int i = 0; i < 4; ++i) {
        int idx = base + t * 4 + i;
        if (idx < n) v += cnt[idx];
    }
    s[t] = v;
    __syncthreads();
    for (int o = 128; o > 0; o >>= 1) {
        if (t < o) s[t] += s[t + o];
        __syncthreads();
    }
    if (t == 0) bsum[blockIdx.x] = s[0];
}

__global__ void scan_top_kernel(int* __restrict__ bsum, int nb) {
    __shared__ int s[256];
    int t = threadIdx.x;
    int v = (t < nb) ? bsum[t] : 0;
    s[t] = v;
    __syncthreads();
    for (int o = 1; o < 256; o <<= 1) {
        int add = (t >= o) ? s[t - o] : 0;
        __syncthreads();
        s[t] += add;
        __syncthreads();
    }
    if (t < nb) bsum[t] = s[t] - v;  // exclusive
}

__global__ void scan_write_kernel(const int* __restrict__ cnt, const int* __restrict__ bsum,
                                  int* __restrict__ off, int n) {
    __shared__ int s[256];
    int base = blockIdx.x * 1024;
    int t = threadIdx.x;
    int v[4];
    int sum = 0;
#pragma unroll
    for (int i = 0; i < 4; ++i) {
        int idx = base + t * 4 + i;
        v[i] = (idx < n) ? cnt[idx] : 0;
        sum += v[i];
    }
    s[t] = sum;
    __syncthreads();
    for (int o = 1; o < 256; o <<= 1) {
        int add = (t >= o) ? s[t - o] : 0;
        __syncthreads();
        s[t] += add;
        __syncthreads();
    }
    int p = bsum[blockIdx.x] + s[t] - sum;
#pragma unroll
    for (int i = 0; i < 4; ++i) {
        int idx = base + t * 4 + i;
        if (idx < n) { off[idx] = p; p += v[i]; }
    }
}

// ---------------- atomic-free scatter: rows grouped by target ----------------
__global__ void scatter2_kernel(const int* __restrict__ rows, const int* __restrict__ cols,
                                const int* __restrict__ rank, const int* __restrict__ ph_col,
                                const int* __restrict__ off, int* __restrict__ rows_buf,
                                int E, int n) {
    int base = blockIdx.x * 1024 + threadIdx.x;
    int k[4], r[4], j[4], e[4];
    bool a[4];
#pragma unroll
    for (int u = 0; u < 4; ++u) {
        e[u] = base + u * 256;
        a[u] = e[u] < E;
        if (a[u]) {
            k[u] = cols[e[u]];
            r[u] = rows[e[u]];
            j[u] = rank[e[u]];
        }
    }
#pragma unroll
    for (int u = 0; u < 4; ++u) {
        if (a[u]) {
            int b = e[u] >> LOG_EPB;
            int pos = off[k[u]] + ph_col[(size_t)b * n + k[u]] + j[u];
            rows_buf[pos] = r[u];
        }
    }
}

// ---------------- linear: x = feat @ W^T + b ----------------
__launch_bounds__(256, 3)
__global__ void gemm_kernel(const float* __restrict__ feat, const float* __restrict__ W,
                            const float* __restrict__ b, float* __restrict__ x, int n) {
    __shared__ float WT[64][128];
    __shared__ float F[32][68];

    const int t = threadIdx.x;
    const int row0 = blockIdx.x * 32;
    const int c0 = (t & 31) * 4;
    const int r0 = (t >> 5) * 4;

    float4 bb = *(const float4*)(b + c0);
    float4 acc0 = bb, acc1 = bb, acc2 = bb, acc3 = bb;

    for (int kh = 0; kh < 2; ++kh) {
        {
            int c = t >> 1;
            int kb = (t & 1) * 32;
            const float4* src = (const float4*)(W + (size_t)c * NFEAT + kh * 64 + kb);
#pragma unroll
            for (int i = 0; i < 8; ++i) {
                float4 w4 = src[i];
                int k = kb + i * 4;
                WT[k + 0][c] = w4.x;
                WT[k + 1][c] = w4.y;
                WT[k + 2][c] = w4.z;
                WT[k + 3][c] = w4.w;
            }
        }
        {
            int r = t >> 3;
            int kb = (t & 7) * 8;
            int gr = row0 + r;
            float4 a = make_float4(0.f, 0.f, 0.f, 0.f);
            float4 d = a;
            if (gr < n) {
                const float4* src = (const float4*)(feat + (size_t)gr * NFEAT + kh * 64 + kb);
                a = src[0];
                d = src[1];
            }
            *(float4*)&F[r][kb] = a;
            *(float4*)&F[r][kb + 4] = d;
        }
        __syncthreads();

#pragma unroll 2
        for (int k = 0; k < 64; k += 4) {
            float4 w0 = *(const float4*)&WT[k + 0][c0];
            float4 w1 = *(const float4*)&WT[k + 1][c0];
            float4 w2 = *(const float4*)&WT[k + 2][c0];
            float4 w3 = *(const float4*)&WT[k + 3][c0];

            float4 f0 = *(const float4*)&F[r0 + 0][k];
            float4 f1 = *(const float4*)&F[r0 + 1][k];
            float4 f2 = *(const float4*)&F[r0 + 2][k];
            float4 f3 = *(const float4*)&F[r0 + 3][k];

            acc0.x = fmaf(f0.x, w0.x, acc0.x); acc0.y = fmaf(f0.x, w0.y, acc0.y);
            acc0.z = fmaf(f0.x, w0.z, acc0.z); acc0.w = fmaf(f0.x, w0.w, acc0.w);
            acc0.x = fmaf(f0.y, w1.x, acc0.x); acc0.y = fmaf(f0.y, w1.y, acc0.y);
            acc0.z = fmaf(f0.y, w1.z, acc0.z); acc0.w = fmaf(f0.y, w1.w, acc0.w);
            acc0.x = fmaf(f0.z, w2.x, acc0.x); acc0.y = fmaf(f0.z, w2.y, acc0.y);
            acc0.z = fmaf(f0.z, w2.z, acc0.z); acc0.w = fmaf(f0.z, w2.w, acc0.w);
            acc0.x = fmaf(f0.w, w3.x, acc0.x); acc0.y = fmaf(f0.w, w3.y, acc0.y);
            acc0.z = fmaf(f0.w, w3.z, acc0.z); acc0.w = fmaf(f0.w, w3.w, acc0.w);

            acc1.x = fmaf(f1.x, w0.x, acc1.x); acc1.y = fmaf(f1.x, w0.y, acc1.y);
            acc1.z = fmaf(f1.x, w0.z, acc1.z); acc1.w = fmaf(f1.x, w0.w, acc1.w);
            acc1.x = fmaf(f1.y, w1.x, acc1.x); acc1.y = fmaf(f1.y, w1.y, acc1.y);
            acc1.z = fmaf(f1.y, w1.z, acc1.z); acc1.w = fmaf(f1.y, w1.w, acc1.w);
            acc1.x = fmaf(f1.z, w2.x, acc1.x); acc1.y = fmaf(f1.z, w2.y, acc1.y);
            acc1.z = fmaf(f1.z, w2.z, acc1.z); acc1.w = fmaf(f1.z, w2.w, acc1.w);
            acc1.x = fmaf(f1.w, w3.x, acc1.x); acc1.y = fmaf(f1.w, w3.y, acc1.y);
            acc1.z = fmaf(f1.w, w3.z, acc1.z); acc1.w = fmaf(f1.w, w3.w, acc1.w);

            acc2.x = fmaf(f2.x, w0.x, acc2.x); acc2.y = fmaf(f2.x, w0.y, acc2.y);
            acc2.z = fmaf(f2.x, w0.z, acc2.z); acc2.w = fmaf(f2.x, w0.w, acc2.w);
            acc2.x = fmaf(f2.y, w1.x, acc2.x); acc2.y = fmaf(f2.y, w1.y, acc2.y);
            acc2.z = fmaf(f2.y, w1.z, acc2.z); acc2.w = fmaf(f2.y, w1.w, acc2.w);
            acc2.x = fmaf(f2.z, w2.x, acc2.x); acc2.y = fmaf(f2.z, w2.y, acc2.y);
            acc2.z = fmaf(f2.z, w2.z, acc2.z); acc2.w = fmaf(f2.z, w2.w, acc2.w);
            acc2.x = fmaf(f2.w, w3.x, acc2.x); acc2.y = fmaf(f2.w, w3.y, acc2.y);
            acc2.z = fmaf(f2.w, w3.z, acc2.z); acc2.w = fmaf(f2.w, w3.w, acc2.w);

            acc3.x = fmaf(f3.x, w0.x, acc3.x); acc3.y = fmaf(f3.x, w0.y, acc3.y);
            acc3.z = fmaf(f3.x, w0.z, acc3.z); acc3.w = fmaf(f3.x, w0.w, acc3.w);
            acc3.x = fmaf(f3.y, w1.x, acc3.x); acc3.y = fmaf(f3.y, w1.y, acc3.y);
            acc3.z = fmaf(f3.y, w1.z, acc3.z); acc3.w = fmaf(f3.y, w1.w, acc3.w);
            acc3.x = fmaf(f3.z, w2.x, acc3.x); acc3.y = fmaf(f3.z, w2.y, acc3.y);
            acc3.z = fmaf(f3.z, w2.z, acc3.z); acc3.w = fmaf(f3.z, w2.w, acc3.w);
            acc3.x = fmaf(f3.w, w3.x, acc3.x); acc3.y = fmaf(f3.w, w3.y, acc3.y);
            acc3.z = fmaf(f3.w, w3.z, acc3.z); acc3.w = fmaf(f3.w, w3.w, acc3.w);
        }
        __syncthreads();
    }

    int gr = row0 + r0;
    if (gr + 0 < n) *(float4*)(x + (size_t)(gr + 0) * NFEAT + c0) = acc0;
    if (gr + 1 < n) *(float4*)(x + (size_t)(gr + 1) * NFEAT + c0) = acc1;
    if (gr + 2 < n) *(float4*)(x + (size_t)(gr + 2) * NFEAT + c0) = acc2;
    if (gr + 3 < n) *(float4*)(x + (size_t)(gr + 3) * NFEAT + c0) = acc3;
}

// ---------------- gather: out[c] = dis[c]^2 * x[c] + sum_{r->c} dis[r]*dis[c]*x[r] ----------------
__launch_bounds__(256)
__global__ void gather_kernel(const int* __restrict__ rows_buf, const int* __restrict__ off,
                              const int* __restrict__ cnt, const float* __restrict__ x,
                              const float* __restrict__ dis, float* __restrict__ out, int n) {
    int w = threadIdx.x >> 6;
    int lane = threadIdx.x & 63;
    int c = blockIdx.x * 4 + w;
    if (c >= n) return;

    float disc = dis[c];
    int start = off[c];
    int len = cnt[c];
    const float2* x2 = (const float2*)x;

    float2 acc;
    {
        float2 xv = x2[(size_t)c * 64 + lane];
        float sl = disc * disc;
        acc.x = xv.x * sl;
        acc.y = xv.y * sl;
    }

    int j = 0;
    for (; j + 1 < len; j += 2) {
        int r0 = rows_buf[start + j];
        int r1 = rows_buf[start + j + 1];
        float n0 = dis[r0] * disc;
        float n1 = dis[r1] * disc;
        float2 a = x2[(size_t)r0 * 64 + lane];
        float2 b = x2[(size_t)r1 * 64 + lane];
        acc.x = fmaf(a.x, n0, acc.x); acc.y = fmaf(a.y, n0, acc.y);
        acc.x = fmaf(b.x, n1, acc.x); acc.y = fmaf(b.y, n1, acc.y);
    }
    if (j < len) {
        int r = rows_buf[start + j];
        float nn = dis[r] * disc;
        float2 a = x2[(size_t)r * 64 + lane];
        acc.x = fmaf(a.x, nn, acc.x); acc.y = fmaf(a.y, nn, acc.y);
    }

    ((float2*)out)[(size_t)c * 64 + lane] = acc;
}

extern "C" void kernel_launch(void* const* d_in, const int* in_sizes, int n_in,
                              void* d_out, int out_size, void* d_ws, size_t ws_size,
                              hipStream_t stream) {
    const float* feat = (const float*)d_in[0];
    const int*   edges = (const int*)d_in[1];
    const float* W = (const float*)d_in[2];
    const float* b = (const float*)d_in[3];
    float* out = (float*)d_out;

    int n = in_sizes[0] / NFEAT;   // 100000
    int E = in_sizes[1] / 2;       // 1600000
    const int* row = edges;        // edges[0] = source
    const int* col = edges + E;    // edges[1] = target

    int NB = (E + EPB - 1) >> LOG_EPB;  // 13

    // workspace layout (all 4-byte elems)
    float* x       = (float*)d_ws;                    // n*128
    float* dis     = x + (size_t)n * NFEAT;           // n
    int*   colcnt  = (int*)(dis + n);                 // n
    int*   off     = colcnt + n;                      // n
    int*   rows_buf= off + n;                         // E
    int*   rank    = rows_buf + E;                    // E
    int*   ph_row  = rank + E;                        // NB*n
    int*   ph_col  = ph_row + (size_t)NB * n;         // NB*n
    int*   bsum    = ph_col + (size_t)NB * n;         // ~128

    int nb = (n + 1023) / 1024;   // 98 scan blocks

    // 1) LDS-privatized partial histograms (+ per-edge local rank for col)
    dim3 hgrid(NB, NCHUNK, 2);
    hist_part_kernel<<<hgrid, 256, 0, stream>>>(row, col, ph_row, ph_col, rank, E, n);

    // 2) per-key reductions: dis (row) / exclusive block-cum + colcnt (col)
    cum_kernel<<<(n + 255) / 256, 256, 0, stream>>>(ph_row, ph_col, dis, colcnt, NB, n);

    // 3) exclusive scan of colcnt -> off
    scan_bsum_kernel<<<nb, 256, 0, stream>>>(colcnt, bsum, n);
    scan_top_kernel<<<1, 256, 0, stream>>>(bsum, nb);
    scan_write_kernel<<<nb, 256, 0, stream>>>(colcnt, bsum, off, n);

    // 4) atomic-free scatter (counting sort of edges by target)
    scatter2_kernel<<<(E + 1023) / 1024, 256, 0, stream>>>(row, col, rank, ph_col, off, rows_buf, E, n);

    // 5) linear transform
    gemm_kernel<<<(n + 31) / 32, 256, 0, stream>>>(feat, W, b, x, n);

    // 6) atomic-free gather (fuses self-loop)
    gather_kernel<<<(n + 3) / 4, 256, 0, stream>>>(rows_buf, off, colcnt, x, dis, out, n);
}

// Round 6
// 412.961 us; speedup vs baseline: 7.9328x; 1.2139x over previous
//
#include <hip/hip_runtime.h>

#define NFEAT 128
#define CH 25600           // keys per chunk (16-bit counters, packed 2/uint)
#define CH2 (CH / 2)       // LDS words: 12800 uints = 50 KB

// ---------------- LDS-privatized partial histograms, 16-bit packed ----------------
// grid: (NB, nchunk, 2). z=0: rows -> ph_row. z=1: cols -> ph_col + rank[e].
__launch_bounds__(256)
__global__ void hist16_kernel(const int* __restrict__ rows, const int* __restrict__ cols,
                              unsigned int* __restrict__ ph_row, unsigned int* __restrict__ ph_col,
                              int* __restrict__ rank, int E, int n, int W, int log_epb) {
    __shared__ unsigned int h[CH2];
    const int b = blockIdx.x;
    const int c0 = blockIdx.y * CH;
    const int z = blockIdx.z;
    const int* __restrict__ keys = z ? cols : rows;
    unsigned int* __restrict__ ph = z ? ph_col : ph_row;

    for (int i = threadIdx.x; i < CH2; i += 256) h[i] = 0;
    __syncthreads();

    const int lo = b << log_epb;
    const int hi = min(E, lo + (1 << log_epb));
    const int t = threadIdx.x;

    int full = (hi - lo) >> 10;  // full 1024-edge groups
    for (int it = 0; it < full; ++it) {
        int e0 = lo + (it << 10) + t * 4;
        int4 kk = *(const int4*)(keys + e0);
        int k0 = kk.x - c0, k1 = kk.y - c0, k2 = kk.z - c0, k3 = kk.w - c0;
        if ((unsigned)k0 < CH) {
            unsigned old = atomicAdd(&h[k0 >> 1], 1u << ((k0 & 1) * 16));
            if (z) rank[e0 + 0] = (old >> ((k0 & 1) * 16)) & 0xffff;
        }
        if ((unsigned)k1 < CH) {
            unsigned old = atomicAdd(&h[k1 >> 1], 1u << ((k1 & 1) * 16));
            if (z) rank[e0 + 1] = (old >> ((k1 & 1) * 16)) & 0xffff;
        }
        if ((unsigned)k2 < CH) {
            unsigned old = atomicAdd(&h[k2 >> 1], 1u << ((k2 & 1) * 16));
            if (z) rank[e0 + 2] = (old >> ((k2 & 1) * 16)) & 0xffff;
        }
        if ((unsigned)k3 < CH) {
            unsigned old = atomicAdd(&h[k3 >> 1], 1u << ((k3 & 1) * 16));
            if (z) rank[e0 + 3] = (old >> ((k3 & 1) * 16)) & 0xffff;
        }
    }
    for (int e = lo + (full << 10) + t; e < hi; e += 256) {
        int k = keys[e] - c0;
        if ((unsigned)k < CH) {
            unsigned old = atomicAdd(&h[k >> 1], 1u << ((k & 1) * 16));
            if (z) rank[e] = (old >> ((k & 1) * 16)) & 0xffff;
        }
    }
    __syncthreads();

    int wbase = c0 >> 1;  // word offset of this chunk
    for (int i = threadIdx.x; i < CH2; i += 256) {
        int w = wbase + i;
        if (w < W) ph[(size_t)b * W + w] = h[i];  // bit-identical packed store
    }
}

// ---------------- per-key: row-sum -> dis; col exclusive-cum over blocks -> colcnt ----------------
__global__ void cum_kernel(const unsigned short* __restrict__ ph_row,
                           unsigned short* __restrict__ ph_col,
                           float* __restrict__ dis, int* __restrict__ colcnt, int NB, int n) {
    int k = blockIdx.x * 256 + threadIdx.x;
    if (k >= n) return;
    int rs = 0;
    for (int b = 0; b < NB; ++b) rs += ph_row[(size_t)b * n + k];
    dis[k] = rsqrtf(1.0f + (float)rs);
    int acc = 0;
    for (int b = 0; b < NB; ++b) {
        int v = ph_col[(size_t)b * n + k];
        ph_col[(size_t)b * n + k] = (unsigned short)acc;  // exclusive prefix (fits: max cnt ~60)
        acc += v;
    }
    colcnt[k] = acc;
}

// ---------------- hierarchical exclusive scan of colcnt -> off ----------------
__global__ void scan_bsum_kernel(const int* __restrict__ cnt, int* __restrict__ bsum, int n) {
    __shared__ int s[256];
    int base = blockIdx.x * 1024;
    int t = threadIdx.x;
    int v = 0;
#pragma unroll
    for (int i = 0; i < 4; ++i) {
        int idx = base + t * 4 + i;
        if (idx < n) v += cnt[idx];
    }
    s[t] = v;
    __syncthreads();
    for (int o = 128; o > 0; o >>= 1) {
        if (t < o) s[t] += s[t + o];
        __syncthreads();
    }
    if (t == 0) bsum[blockIdx.x] = s[0];
}

__global__ void scan_top_kernel(int* __restrict__ bsum, int nb) {
    __shared__ int s[256];
    int t = threadIdx.x;
    int v = (t < nb) ? bsum[t] : 0;
    s[t] = v;
    __syncthreads();
    for (int o = 1; o < 256; o <<= 1) {
        int add = (t >= o) ? s[t - o] : 0;
        __syncthreads();
        s[t] += add;
        __syncthreads();
    }
    if (t < nb) bsum[t] = s[t] - v;  // exclusive
}

__global__ void scan_write_kernel(const int* __restrict__ cnt, const int* __restrict__ bsum,
                                  int* __restrict__ off, int n) {
    __shared__ int s[256];
    int base = blockIdx.x * 1024;
    int t = threadIdx.x;
    int v[4];
    int sum = 0;
#pragma unroll
    for (int i = 0; i < 4; ++i) {
        int idx = base + t * 4 + i;
        v[i] = (idx < n) ? cnt[idx] : 0;
        sum += v[i];
    }
    s[t] = sum;
    __syncthreads();
    for (int o = 1; o < 256; o <<= 1) {
        int add = (t >= o) ? s[t - o] : 0;
        __syncthreads();
        s[t] += add;
        __syncthreads();
    }
    int p = bsum[blockIdx.x] + s[t] - sum;
#pragma unroll
    for (int i = 0; i < 4; ++i) {
        int idx = base + t * 4 + i;
        if (idx < n) { off[idx] = p; p += v[i]; }
    }
}

// ---------------- atomic-free scatter: rows grouped by target ----------------
__global__ void scatter2_kernel(const int* __restrict__ rows, const int* __restrict__ cols,
                                const int* __restrict__ rank, const unsigned short* __restrict__ ph_col,
                                const int* __restrict__ off, int* __restrict__ rows_buf,
                                int E, int n, int log_epb) {
    int base = blockIdx.x * 1024 + threadIdx.x;
#pragma unroll
    for (int u = 0; u < 4; ++u) {
        int e = base + u * 256;
        if (e < E) {
            int k = cols[e];
            int b = e >> log_epb;
            int pos = off[k] + (int)ph_col[(size_t)b * n + k] + rank[e];
            rows_buf[pos] = rows[e];
        }
    }
}

// ---------------- linear: x = feat @ W^T + b ----------------
__launch_bounds__(256, 3)
__global__ void gemm_kernel(const float* __restrict__ feat, const float* __restrict__ W,
                            const float* __restrict__ b, float* __restrict__ x, int n) {
    __shared__ float WT[64][128];
    __shared__ float F[32][68];

    const int t = threadIdx.x;
    const int row0 = blockIdx.x * 32;
    const int c0 = (t & 31) * 4;
    const int r0 = (t >> 5) * 4;

    float4 bb = *(const float4*)(b + c0);
    float4 acc0 = bb, acc1 = bb, acc2 = bb, acc3 = bb;

    for (int kh = 0; kh < 2; ++kh) {
        {
            int c = t >> 1;
            int kb = (t & 1) * 32;
            const float4* src = (const float4*)(W + (size_t)c * NFEAT + kh * 64 + kb);
#pragma unroll
            for (int i = 0; i < 8; ++i) {
                float4 w4 = src[i];
                int k = kb + i * 4;
                WT[k + 0][c] = w4.x;
                WT[k + 1][c] = w4.y;
                WT[k + 2][c] = w4.z;
                WT[k + 3][c] = w4.w;
            }
        }
        {
            int r = t >> 3;
            int kb = (t & 7) * 8;
            int gr = row0 + r;
            float4 a = make_float4(0.f, 0.f, 0.f, 0.f);
            float4 d = a;
            if (gr < n) {
                const float4* src = (const float4*)(feat + (size_t)gr * NFEAT + kh * 64 + kb);
                a = src[0];
                d = src[1];
            }
            *(float4*)&F[r][kb] = a;
            *(float4*)&F[r][kb + 4] = d;
        }
        __syncthreads();

#pragma unroll 2
        for (int k = 0; k < 64; k += 4) {
            float4 w0 = *(const float4*)&WT[k + 0][c0];
            float4 w1 = *(const float4*)&WT[k + 1][c0];
            float4 w2 = *(const float4*)&WT[k + 2][c0];
            float4 w3 = *(const float4*)&WT[k + 3][c0];

            float4 f0 = *(const float4*)&F[r0 + 0][k];
            float4 f1 = *(const float4*)&F[r0 + 1][k];
            float4 f2 = *(const float4*)&F[r0 + 2][k];
            float4 f3 = *(const float4*)&F[r0 + 3][k];

            acc0.x = fmaf(f0.x, w0.x, acc0.x); acc0.y = fmaf(f0.x, w0.y, acc0.y);
            acc0.z = fmaf(f0.x, w0.z, acc0.z); acc0.w = fmaf(f0.x, w0.w, acc0.w);
            acc0.x = fmaf(f0.y, w1.x, acc0.x); acc0.y = fmaf(f0.y, w1.y, acc0.y);
            acc0.z = fmaf(f0.y, w1.z, acc0.z); acc0.w = fmaf(f0.y, w1.w, acc0.w);
            acc0.x = fmaf(f0.z, w2.x, acc0.x); acc0.y = fmaf(f0.z, w2.y, acc0.y);
            acc0.z = fmaf(f0.z, w2.z, acc0.z); acc0.w = fmaf(f0.z, w2.w, acc0.w);
            acc0.x = fmaf(f0.w, w3.x, acc0.x); acc0.y = fmaf(f0.w, w3.y, acc0.y);
            acc0.z = fmaf(f0.w, w3.z, acc0.z); acc0.w = fmaf(f0.w, w3.w, acc0.w);

            acc1.x = fmaf(f1.x, w0.x, acc1.x); acc1.y = fmaf(f1.x, w0.y, acc1.y);
            acc1.z = fmaf(f1.x, w0.z, acc1.z); acc1.w = fmaf(f1.x, w0.w, acc1.w);
            acc1.x = fmaf(f1.y, w1.x, acc1.x); acc1.y = fmaf(f1.y, w1.y, acc1.y);
            acc1.z = fmaf(f1.y, w1.z, acc1.z); acc1.w = fmaf(f1.y, w1.w, acc1.w);
            acc1.x = fmaf(f1.z, w2.x, acc1.x); acc1.y = fmaf(f1.z, w2.y, acc1.y);
            acc1.z = fmaf(f1.z, w2.z, acc1.z); acc1.w = fmaf(f1.z, w2.w, acc1.w);
            acc1.x = fmaf(f1.w, w3.x, acc1.x); acc1.y = fmaf(f1.w, w3.y, acc1.y);
            acc1.z = fmaf(f1.w, w3.z, acc1.z); acc1.w = fmaf(f1.w, w3.w, acc1.w);

            acc2.x = fmaf(f2.x, w0.x, acc2.x); acc2.y = fmaf(f2.x, w0.y, acc2.y);
            acc2.z = fmaf(f2.x, w0.z, acc2.z); acc2.w = fmaf(f2.x, w0.w, acc2.w);
            acc2.x = fmaf(f2.y, w1.x, acc2.x); acc2.y = fmaf(f2.y, w1.y, acc2.y);
            acc2.z = fmaf(f2.y, w1.z, acc2.z); acc2.w = fmaf(f2.y, w1.w, acc2.w);
            acc2.x = fmaf(f2.z, w2.x, acc2.x); acc2.y = fmaf(f2.z, w2.y, acc2.y);
            acc2.z = fmaf(f2.z, w2.z, acc2.z); acc2.w = fmaf(f2.z, w2.w, acc2.w);
            acc2.x = fmaf(f2.w, w3.x, acc2.x); acc2.y = fmaf(f2.w, w3.y, acc2.y);
            acc2.z = fmaf(f2.w, w3.z, acc2.z); acc2.w = fmaf(f2.w, w3.w, acc2.w);

            acc3.x = fmaf(f3.x, w0.x, acc3.x); acc3.y = fmaf(f3.x, w0.y, acc3.y);
            acc3.z = fmaf(f3.x, w0.z, acc3.z); acc3.w = fmaf(f3.x, w0.w, acc3.w);
            acc3.x = fmaf(f3.y, w1.x, acc3.x); acc3.y = fmaf(f3.y, w1.y, acc3.y);
            acc3.z = fmaf(f3.y, w1.z, acc3.z); acc3.w = fmaf(f3.y, w1.w, acc3.w);
            acc3.x = fmaf(f3.z, w2.x, acc3.x); acc3.y = fmaf(f3.z, w2.y, acc3.y);
            acc3.z = fmaf(f3.z, w2.z, acc3.z); acc3.w = fmaf(f3.z, w2.w, acc3.w);
            acc3.x = fmaf(f3.w, w3.x, acc3.x); acc3.y = fmaf(f3.w, w3.y, acc3.y);
            acc3.z = fmaf(f3.w, w3.z, acc3.z); acc3.w = fmaf(f3.w, w3.w, acc3.w);
        }
        __syncthreads();
    }

    int gr = row0 + r0;
    if (gr + 0 < n) *(float4*)(x + (size_t)(gr + 0) * NFEAT + c0) = acc0;
    if (gr + 1 < n) *(float4*)(x + (size_t)(gr + 1) * NFEAT + c0) = acc1;
    if (gr + 2 < n) *(float4*)(x + (size_t)(gr + 2) * NFEAT + c0) = acc2;
    if (gr + 3 < n) *(float4*)(x + (size_t)(gr + 3) * NFEAT + c0) = acc3;
}

// ---------------- gather: lane-parallel metadata prefetch + shfl broadcast ----------------
__launch_bounds__(256)
__global__ void gather_kernel(const int* __restrict__ rows_buf, const int* __restrict__ off,
                              const int* __restrict__ cnt, const float* __restrict__ x,
                              const float* __restrict__ dis, float* __restrict__ out, int n) {
    int lane = threadIdx.x & 63;
    int c = blockIdx.x * 4 + (threadIdx.x >> 6);
    if (c >= n) return;

    float disc = dis[c];
    int start = off[c];
    int len = cnt[c];
    const float2* x2 = (const float2*)x;

    float2 acc;
    {
        float2 xv = x2[(size_t)c * 64 + lane];
        float sl = disc * disc;  // self-loop norm
        acc.x = xv.x * sl;
        acc.y = xv.y * sl;
    }

    for (int base = 0; base < len; base += 64) {
        int m = min(64, len - base);
        int r_l = 0;
        float nrm_l = 0.0f;
        if (lane < m) {
            r_l = rows_buf[start + base + lane];
            nrm_l = dis[r_l] * disc;
        }
#pragma unroll 4
        for (int j = 0; j < m; ++j) {
            int r = __shfl(r_l, j);
            float nm = __shfl(nrm_l, j);
            float2 a = x2[(size_t)r * 64 + lane];
            acc.x = fmaf(a.x, nm, acc.x);
            acc.y = fmaf(a.y, nm, acc.y);
        }
    }

    ((float2*)out)[(size_t)c * 64 + lane] = acc;
}

extern "C" void kernel_launch(void* const* d_in, const int* in_sizes, int n_in,
                              void* d_out, int out_size, void* d_ws, size_t ws_size,
                              hipStream_t stream) {
    const float* feat = (const float*)d_in[0];
    const int*   edges = (const int*)d_in[1];
    const float* W = (const float*)d_in[2];
    const float* b = (const float*)d_in[3];
    float* out = (float*)d_out;

    int n = in_sizes[0] / NFEAT;   // 100000
    int E = in_sizes[1] / 2;       // 1600000
    const int* row = edges;        // edges[0] = source
    const int* col = edges + E;    // edges[1] = target

    int Wd = (n + 1) / 2;                 // packed words per slab
    int nchunk = (n + CH - 1) / CH;       // 4

    // fixed workspace (4B units): x | dis | colcnt | off | rows_buf | rank | bsum
    size_t fixed = (size_t)n * NFEAT + 3 * (size_t)n + 2 * (size_t)E + 256;

    // pick largest parallelism that fits ws: log_epb in {14, 15, 16}
    int log_epb = 16;
    int NB = (E + (1 << 16) - 1) >> 16;
    for (int lg = 14; lg <= 16; ++lg) {
        int nb_try = (E + (1 << lg) - 1) >> lg;
        size_t words = fixed + 2 * (size_t)nb_try * Wd;
        if (words * 4 <= ws_size) { log_epb = lg; NB = nb_try; break; }
    }

    float* x        = (float*)d_ws;                    // n*128
    float* dis      = x + (size_t)n * NFEAT;           // n
    int*   colcnt   = (int*)(dis + n);                 // n
    int*   off      = colcnt + n;                      // n
    int*   rows_buf = off + n;                         // E
    int*   rank     = rows_buf + E;                    // E
    int*   bsum     = rank + E;                        // 256
    unsigned int* ph_row = (unsigned int*)(bsum + 256);          // NB*Wd words
    unsigned int* ph_col = ph_row + (size_t)NB * Wd;             // NB*Wd words

    int nb = (n + 1023) / 1024;   // scan blocks

    // 1) partial histograms (rows; cols + rank)
    dim3 hgrid(NB, nchunk, 2);
    hist16_kernel<<<hgrid, 256, 0, stream>>>(row, col, ph_row, ph_col, rank, E, n, Wd, log_epb);

    // 2) per-key reductions: dis (rows) / exclusive block-prefix + colcnt (cols)
    cum_kernel<<<(n + 255) / 256, 256, 0, stream>>>((const unsigned short*)ph_row,
                                                    (unsigned short*)ph_col, dis, colcnt, NB, n);

    // 3) exclusive scan of colcnt -> off
    scan_bsum_kernel<<<nb, 256, 0, stream>>>(colcnt, bsum, n);
    scan_top_kernel<<<1, 256, 0, stream>>>(bsum, nb);
    scan_write_kernel<<<nb, 256, 0, stream>>>(colcnt, bsum, off, n);

    // 4) atomic-free scatter (counting sort of edges by target)
    scatter2_kernel<<<(E + 1023) / 1024, 256, 0, stream>>>(row, col, rank,
                                                           (const unsigned short*)ph_col,
                                                           off, rows_buf, E, n, log_epb);

    // 5) linear transform
    gemm_kernel<<<(n + 31) / 32, 256, 0, stream>>>(feat, W, b, x, n);

    // 6) atomic-free gather (fuses self-loop)
    gather_kernel<<<(n + 3) / 4, 256, 0, stream>>>(rows_buf, off, colcnt, x, dis, out, n);
}

// Round 9
// 395.224 us; speedup vs baseline: 8.2888x; 1.0449x over previous
//
#include <hip/hip_runtime.h>

#define NFEAT 128
#define CH 25600           // keys per chunk (16-bit counters, packed 2/uint)
#define CH2 (CH / 2)       // LDS words: 12800 uints = 50 KB

typedef __attribute__((ext_vector_type(8))) short bf16x8;
typedef __attribute__((ext_vector_type(4))) float f32x4;

static __device__ __forceinline__ short f2bf(float f) {
    unsigned u = __builtin_bit_cast(unsigned, f);
    unsigned r = (u + 0x7fff + ((u >> 16) & 1)) >> 16;  // RNE
    return (short)r;
}
static __device__ __forceinline__ float bf2f(short s) {
    unsigned u = ((unsigned)(unsigned short)s) << 16;
    return __builtin_bit_cast(float, u);
}

// ---------------- LDS-privatized partial histograms, 16-bit packed ----------------
__launch_bounds__(256)
__global__ void hist16_kernel(const int* __restrict__ rows, const int* __restrict__ cols,
                              unsigned int* __restrict__ ph_row, unsigned int* __restrict__ ph_col,
                              int* __restrict__ rank, int E, int n, int W, int log_epb) {
    __shared__ unsigned int h[CH2];
    const int b = blockIdx.x;
    const int c0 = blockIdx.y * CH;
    const int z = blockIdx.z;
    const int* __restrict__ keys = z ? cols : rows;
    unsigned int* __restrict__ ph = z ? ph_col : ph_row;

    for (int i = threadIdx.x; i < CH2; i += 256) h[i] = 0;
    __syncthreads();

    const int lo = b << log_epb;
    const int hi = min(E, lo + (1 << log_epb));
    const int t = threadIdx.x;

    int full = (hi - lo) >> 10;
    for (int it = 0; it < full; ++it) {
        int e0 = lo + (it << 10) + t * 4;
        int4 kk = *(const int4*)(keys + e0);
        int k0 = kk.x - c0, k1 = kk.y - c0, k2 = kk.z - c0, k3 = kk.w - c0;
        if ((unsigned)k0 < CH) {
            unsigned old = atomicAdd(&h[k0 >> 1], 1u << ((k0 & 1) * 16));
            if (z) rank[e0 + 0] = (old >> ((k0 & 1) * 16)) & 0xffff;
        }
        if ((unsigned)k1 < CH) {
            unsigned old = atomicAdd(&h[k1 >> 1], 1u << ((k1 & 1) * 16));
            if (z) rank[e0 + 1] = (old >> ((k1 & 1) * 16)) & 0xffff;
        }
        if ((unsigned)k2 < CH) {
            unsigned old = atomicAdd(&h[k2 >> 1], 1u << ((k2 & 1) * 16));
            if (z) rank[e0 + 2] = (old >> ((k2 & 1) * 16)) & 0xffff;
        }
        if ((unsigned)k3 < CH) {
            unsigned old = atomicAdd(&h[k3 >> 1], 1u << ((k3 & 1) * 16));
            if (z) rank[e0 + 3] = (old >> ((k3 & 1) * 16)) & 0xffff;
        }
    }
    for (int e = lo + (full << 10) + t; e < hi; e += 256) {
        int k = keys[e] - c0;
        if ((unsigned)k < CH) {
            unsigned old = atomicAdd(&h[k >> 1], 1u << ((k & 1) * 16));
            if (z) rank[e] = (old >> ((k & 1) * 16)) & 0xffff;
        }
    }
    __syncthreads();

    int wbase = c0 >> 1;
    for (int i = threadIdx.x; i < CH2; i += 256) {
        int w = wbase + i;
        if (w < W) ph[(size_t)b * W + w] = h[i];
    }
}

// ---------------- per-key: row-sum -> dis; col exclusive-cum over blocks -> colcnt ----------------
__global__ void cum_kernel(const unsigned short* __restrict__ ph_row,
                           unsigned short* __restrict__ ph_col,
                           float* __restrict__ dis, int* __restrict__ colcnt, int NB, int n) {
    int k = blockIdx.x * 256 + threadIdx.x;
    if (k >= n) return;
    int rs = 0;
    for (int b = 0; b < NB; ++b) rs += ph_row[(size_t)b * n + k];
    dis[k] = rsqrtf(1.0f + (float)rs);
    int acc = 0;
    for (int b = 0; b < NB; ++b) {
        int v = ph_col[(size_t)b * n + k];
        ph_col[(size_t)b * n + k] = (unsigned short)acc;
        acc += v;
    }
    colcnt[k] = acc;
}

// ---------------- hierarchical exclusive scan of colcnt -> off ----------------
__global__ void scan_bsum_kernel(const int* __restrict__ cnt, int* __restrict__ bsum, int n) {
    __shared__ int s[256];
    int base = blockIdx.x * 1024;
    int t = threadIdx.x;
    int v = 0;
#pragma unroll
    for (int i = 0; i < 4; ++i) {
        int idx = base + t * 4 + i;
        if (idx < n) v += cnt[idx];
    }
    s[t] = v;
    __syncthreads();
    for (int o = 128; o > 0; o >>= 1) {
        if (t < o) s[t] += s[t + o];
        __syncthreads();
    }
    if (t == 0) bsum[blockIdx.x] = s[0];
}

__global__ void scan_top_kernel(int* __restrict__ bsum, int nb) {
    __shared__ int s[256];
    int t = threadIdx.x;
    int v = (t < nb) ? bsum[t] : 0;
    s[t] = v;
    __syncthreads();
    for (int o = 1; o < 256; o <<= 1) {
        int add = (t >= o) ? s[t - o] : 0;
        __syncthreads();
        s[t] += add;
        __syncthreads();
    }
    if (t < nb) bsum[t] = s[t] - v;
}

__global__ void scan_write_kernel(const int* __restrict__ cnt, const int* __restrict__ bsum,
                                  int* __restrict__ off, int n) {
    __shared__ int s[256];
    int base = blockIdx.x * 1024;
    int t = threadIdx.x;
    int v[4];
    int sum = 0;
#pragma unroll
    for (int i = 0; i < 4; ++i) {
        int idx = base + t * 4 + i;
        v[i] = (idx < n) ? cnt[idx] : 0;
        sum += v[i];
    }
    s[t] = sum;
    __syncthreads();
    for (int o = 1; o < 256; o <<= 1) {
        int add = (t >= o) ? s[t - o] : 0;
        __syncthreads();
        s[t] += add;
        __syncthreads();
    }
    int p = bsum[blockIdx.x] + s[t] - sum;
#pragma unroll
    for (int i = 0; i < 4; ++i) {
        int idx = base + t * 4 + i;
        if (idx < n) { off[idx] = p; p += v[i]; }
    }
}

// ---------------- atomic-free scatter: rows grouped by target ----------------
__global__ void scatter2_kernel(const int* __restrict__ rows, const int* __restrict__ cols,
                                const int* __restrict__ rank, const unsigned short* __restrict__ ph_col,
                                const int* __restrict__ off, int* __restrict__ rows_buf,
                                int E, int n, int log_epb) {
    int base = blockIdx.x * 1024 + threadIdx.x;
#pragma unroll
    for (int u = 0; u < 4; ++u) {
        int e = base + u * 256;
        if (e < E) {
            int k = cols[e];
            int b = e >> log_epb;
            int pos = off[k] + (int)ph_col[(size_t)b * n + k] + rank[e];
            rows_buf[pos] = rows[e];
        }
    }
}

// ---------------- linear via MFMA, split-bf16 fp32 emulation ----------------
// x = F (M,128) @ W^T (128,128) + b. A=F split hi/lo bf16; B=W^T split hi/lo.
// Per 16x16x32 bf16 MFMA: D += A_hi*B_hi + A_hi*B_lo + A_lo*B_hi (lo*lo ~2^-18, dropped).
// LDS holds W pre-packed as B-fragments: frag(ct,kq,lane) = Wt[k=kq*32+(lane>>4)*8+i][col=ct*16+(lane&15)].
__launch_bounds__(256, 2)
__global__ void gemm_mfma_kernel(const float* __restrict__ feat, const float* __restrict__ W,
                                 const float* __restrict__ b, float* __restrict__ x, int n) {
    __shared__ short whi[16384];  // 8ct * 4kq * 64lane * 8 = 32 KB
    __shared__ short wlo[16384];  // 32 KB

    const int t = threadIdx.x;

    // ---- convert W into pre-packed B-fragments (hi/lo) ----
    {
        int c = t >> 1;                 // W row = output channel (Wt col)
        int kbase = (t & 1) * 64;
        int ct = c >> 4;
        int cl = c & 15;
#pragma unroll
        for (int kc = 0; kc < 8; ++kc) {
            int k0 = kbase + kc * 8;
            const float4* src = (const float4*)(W + (size_t)c * NFEAT + k0);
            float4 fa = src[0];
            float4 fb = src[1];
            float fv[8] = {fa.x, fa.y, fa.z, fa.w, fb.x, fb.y, fb.z, fb.w};
            short h8[8], l8[8];
#pragma unroll
            for (int i = 0; i < 8; ++i) {
                short hi = f2bf(fv[i]);
                h8[i] = hi;
                l8[i] = f2bf(fv[i] - bf2f(hi));
            }
            int kq = k0 >> 5;
            int lane = ((k0 & 31) >> 3) * 16 + cl;
            int idx = ((ct * 4 + kq) * 64 + lane) * 8;
            *(bf16x8*)&whi[idx] = *(bf16x8*)h8;
            *(bf16x8*)&wlo[idx] = *(bf16x8*)l8;
        }
    }
    __syncthreads();

    // ---- per-wave 16-row stripe ----
    const int lane = t & 63;
    const int w = t >> 6;
    const int r0 = blockIdx.x * 64 + w * 16;
    const int arow = r0 + (lane & 15);
    const int koff = (lane >> 4) * 8;

    bf16x8 ahi[4], alo[4];
#pragma unroll
    for (int kq = 0; kq < 4; ++kq) {
        float fv[8] = {0, 0, 0, 0, 0, 0, 0, 0};
        if (arow < n) {
            const float4* src = (const float4*)(feat + (size_t)arow * NFEAT + kq * 32 + koff);
            float4 fa = src[0];
            float4 fb = src[1];
            fv[0] = fa.x; fv[1] = fa.y; fv[2] = fa.z; fv[3] = fa.w;
            fv[4] = fb.x; fv[5] = fb.y; fv[6] = fb.z; fv[7] = fb.w;
        }
        short h8[8], l8[8];
#pragma unroll
        for (int i = 0; i < 8; ++i) {
            short hi = f2bf(fv[i]);
            h8[i] = hi;
            l8[i] = f2bf(fv[i] - bf2f(hi));
        }
        ahi[kq] = *(bf16x8*)h8;
        alo[kq] = *(bf16x8*)l8;
    }

#pragma unroll
    for (int ct = 0; ct < 8; ++ct) {
        f32x4 acc = {0.f, 0.f, 0.f, 0.f};
#pragma unroll
        for (int kq = 0; kq < 4; ++kq) {
            int idx = ((ct * 4 + kq) * 64 + lane) * 8;
            bf16x8 bh = *(const bf16x8*)&whi[idx];
            bf16x8 bl = *(const bf16x8*)&wlo[idx];
            acc = __builtin_amdgcn_mfma_f32_16x16x32_bf16(ahi[kq], bh, acc, 0, 0, 0);
            acc = __builtin_amdgcn_mfma_f32_16x16x32_bf16(alo[kq], bh, acc, 0, 0, 0);
            acc = __builtin_amdgcn_mfma_f32_16x16x32_bf16(ahi[kq], bl, acc, 0, 0, 0);
        }
        int col = ct * 16 + (lane & 15);
        float bb = b[col];
#pragma unroll
        for (int reg = 0; reg < 4; ++reg) {
            int row = r0 + (lane >> 4) * 4 + reg;
            if (row < n) x[(size_t)row * NFEAT + col] = acc[reg] + bb;
        }
    }
}

// ---------------- gather: 2 edges/iter, float4 lanes, shfl broadcast ----------------
__launch_bounds__(256)
__global__ void gather_kernel(const int* __restrict__ rows_buf, const int* __restrict__ off,
                              const int* __restrict__ cnt, const float* __restrict__ x,
                              const float* __restrict__ dis, float* __restrict__ out, int n) {
    int lane = threadIdx.x & 63;
    int h = lane >> 5;        // half-wave id: processes edge 2j+h
    int fl = lane & 31;       // float4 feature index
    int c = blockIdx.x * 4 + (threadIdx.x >> 6);
    if (c >= n) return;

    float disc = dis[c];
    int start = off[c];
    int len = cnt[c];
    const float4* x4 = (const float4*)x;

    float4 acc = make_float4(0.f, 0.f, 0.f, 0.f);
    if (h == 0) {  // self-loop counted once
        float4 xv = x4[(size_t)c * 32 + fl];
        float sl = disc * disc;
        acc.x = xv.x * sl; acc.y = xv.y * sl; acc.z = xv.z * sl; acc.w = xv.w * sl;
    }

    for (int base = 0; base < len; base += 64) {
        int m = min(64, len - base);
        int r_l = 0;
        float nrm_l = 0.0f;
        if (lane < m) {
            r_l = rows_buf[start + base + lane];
            nrm_l = dis[r_l] * disc;
        }
        int pairs = (m + 1) >> 1;
#pragma unroll 4
        for (int jj = 0; jj < pairs; ++jj) {
            int src = 2 * jj + h;
            int r = __shfl(r_l, src);
            float nm = __shfl(nrm_l, src);   // 0 for out-of-range tail lanes
            float4 a = x4[(size_t)r * 32 + fl];
            acc.x = fmaf(a.x, nm, acc.x);
            acc.y = fmaf(a.y, nm, acc.y);
            acc.z = fmaf(a.z, nm, acc.z);
            acc.w = fmaf(a.w, nm, acc.w);
        }
    }

    // combine halves (features are duplicated across halves)
    acc.x += __shfl_xor(acc.x, 32);
    acc.y += __shfl_xor(acc.y, 32);
    acc.z += __shfl_xor(acc.z, 32);
    acc.w += __shfl_xor(acc.w, 32);

    if (h == 0) ((float4*)out)[(size_t)c * 32 + fl] = acc;
}

extern "C" void kernel_launch(void* const* d_in, const int* in_sizes, int n_in,
                              void* d_out, int out_size, void* d_ws, size_t ws_size,
                              hipStream_t stream) {
    const float* feat = (const float*)d_in[0];
    const int*   edges = (const int*)d_in[1];
    const float* W = (const float*)d_in[2];
    const float* b = (const float*)d_in[3];
    float* out = (float*)d_out;

    int n = in_sizes[0] / NFEAT;   // 100000
    int E = in_sizes[1] / 2;       // 1600000
    const int* row = edges;        // edges[0] = source
    const int* col = edges + E;    // edges[1] = target

    int Wd = (n + 1) / 2;
    int nchunk = (n + CH - 1) / CH;

    size_t fixed = (size_t)n * NFEAT + 3 * (size_t)n + 2 * (size_t)E + 256;
    int log_epb = 16;
    int NB = (E + (1 << 16) - 1) >> 16;
    for (int lg = 14; lg <= 16; ++lg) {
        int nb_try = (E + (1 << lg) - 1) >> lg;
        size_t words = fixed + 2 * (size_t)nb_try * Wd;
        if (words * 4 <= ws_size) { log_epb = lg; NB = nb_try; break; }
    }

    float* x        = (float*)d_ws;
    float* dis      = x + (size_t)n * NFEAT;
    int*   colcnt   = (int*)(dis + n);
    int*   off      = colcnt + n;
    int*   rows_buf = off + n;
    int*   rank     = rows_buf + E;
    int*   bsum     = rank + E;
    unsigned int* ph_row = (unsigned int*)(bsum + 256);
    unsigned int* ph_col = ph_row + (size_t)NB * Wd;

    int nb = (n + 1023) / 1024;

    dim3 hgrid(NB, nchunk, 2);
    hist16_kernel<<<hgrid, 256, 0, stream>>>(row, col, ph_row, ph_col, rank, E, n, Wd, log_epb);

    cum_kernel<<<(n + 255) / 256, 256, 0, stream>>>((const unsigned short*)ph_row,
                                                    (unsigned short*)ph_col, dis, colcnt, NB, n);

    scan_bsum_kernel<<<nb, 256, 0, stream>>>(colcnt, bsum, n);
    scan_top_kernel<<<1, 256, 0, stream>>>(bsum, nb);
    scan_write_kernel<<<nb, 256, 0, stream>>>(colcnt, bsum, off, n);

    scatter2_kernel<<<(E + 1023) / 1024, 256, 0, stream>>>(row, col, rank,
                                                           (const unsigned short*)ph_col,
                                                           off, rows_buf, E, n, log_epb);

    gemm_mfma_kernel<<<(n + 63) / 64, 256, 0, stream>>>(feat, W, b, x, n);

    gather_kernel<<<(n + 3) / 4, 256, 0, stream>>>(rows_buf, off, colcnt, x, dis, out, n);
}

// Round 12
// 335.283 us; speedup vs baseline: 9.7707x; 1.1788x over previous
//
#include <hip/hip_runtime.h>

#define NFEAT 128
#define CH 25600           // keys per chunk (16-bit counters, packed 2/uint)
#define CH2 (CH / 2)       // LDS words: 12800 uints = 50 KB

typedef __attribute__((ext_vector_type(8))) short bf16x8;
typedef __attribute__((ext_vector_type(4))) float f32x4;

static __device__ __forceinline__ short f2bf(float f) {
    unsigned u = __builtin_bit_cast(unsigned, f);
    unsigned r = (u + 0x7fff + ((u >> 16) & 1)) >> 16;  // RNE
    return (short)r;
}
static __device__ __forceinline__ float bflo(unsigned u) {
    return __builtin_bit_cast(float, u << 16);
}
static __device__ __forceinline__ float bfhi(unsigned u) {
    return __builtin_bit_cast(float, u & 0xffff0000u);
}

// ---------------- LDS-privatized partial histograms, 16-bit packed ----------------
__launch_bounds__(256)
__global__ void hist16_kernel(const int* __restrict__ rows, const int* __restrict__ cols,
                              unsigned int* __restrict__ ph_row, unsigned int* __restrict__ ph_col,
                              int* __restrict__ rank, int E, int n, int W, int log_epb) {
    __shared__ unsigned int h[CH2];
    const int b = blockIdx.x;
    const int c0 = blockIdx.y * CH;
    const int z = blockIdx.z;
    const int* __restrict__ keys = z ? cols : rows;
    unsigned int* __restrict__ ph = z ? ph_col : ph_row;

    for (int i = threadIdx.x; i < CH2; i += 256) h[i] = 0;
    __syncthreads();

    const int lo = b << log_epb;
    const int hi = min(E, lo + (1 << log_epb));
    const int t = threadIdx.x;

    int full = (hi - lo) >> 10;
    for (int it = 0; it < full; ++it) {
        int e0 = lo + (it << 10) + t * 4;
        int4 kk = *(const int4*)(keys + e0);
        int k0 = kk.x - c0, k1 = kk.y - c0, k2 = kk.z - c0, k3 = kk.w - c0;
        if ((unsigned)k0 < CH) {
            unsigned old = atomicAdd(&h[k0 >> 1], 1u << ((k0 & 1) * 16));
            if (z) rank[e0 + 0] = (old >> ((k0 & 1) * 16)) & 0xffff;
        }
        if ((unsigned)k1 < CH) {
            unsigned old = atomicAdd(&h[k1 >> 1], 1u << ((k1 & 1) * 16));
            if (z) rank[e0 + 1] = (old >> ((k1 & 1) * 16)) & 0xffff;
        }
        if ((unsigned)k2 < CH) {
            unsigned old = atomicAdd(&h[k2 >> 1], 1u << ((k2 & 1) * 16));
            if (z) rank[e0 + 2] = (old >> ((k2 & 1) * 16)) & 0xffff;
        }
        if ((unsigned)k3 < CH) {
            unsigned old = atomicAdd(&h[k3 >> 1], 1u << ((k3 & 1) * 16));
            if (z) rank[e0 + 3] = (old >> ((k3 & 1) * 16)) & 0xffff;
        }
    }
    for (int e = lo + (full << 10) + t; e < hi; e += 256) {
        int k = keys[e] - c0;
        if ((unsigned)k < CH) {
            unsigned old = atomicAdd(&h[k >> 1], 1u << ((k & 1) * 16));
            if (z) rank[e] = (old >> ((k & 1) * 16)) & 0xffff;
        }
    }
    __syncthreads();

    int wbase = c0 >> 1;
    for (int i = threadIdx.x; i < CH2; i += 256) {
        int w = wbase + i;
        if (w < W) ph[(size_t)b * W + w] = h[i];
    }
}

// ---------------- per-key: row-sum -> dis; col exclusive-cum over blocks -> colcnt ----------------
__global__ void cum_kernel(const unsigned short* __restrict__ ph_row,
                           unsigned short* __restrict__ ph_col,
                           float* __restrict__ dis, int* __restrict__ colcnt, int NB, int n) {
    int k = blockIdx.x * 256 + threadIdx.x;
    if (k >= n) return;
    int rs = 0;
    for (int b = 0; b < NB; ++b) rs += ph_row[(size_t)b * n + k];
    dis[k] = rsqrtf(1.0f + (float)rs);
    int acc = 0;
    for (int b = 0; b < NB; ++b) {
        int v = ph_col[(size_t)b * n + k];
        ph_col[(size_t)b * n + k] = (unsigned short)acc;
        acc += v;
    }
    colcnt[k] = acc;
}

// ---------------- hierarchical exclusive scan of colcnt -> off ----------------
__global__ void scan_bsum_kernel(const int* __restrict__ cnt, int* __restrict__ bsum, int n) {
    __shared__ int s[256];
    int base = blockIdx.x * 1024;
    int t = threadIdx.x;
    int v = 0;
#pragma unroll
    for (int i = 0; i < 4; ++i) {
        int idx = base + t * 4 + i;
        if (idx < n) v += cnt[idx];
    }
    s[t] = v;
    __syncthreads();
    for (int o = 128; o > 0; o >>= 1) {
        if (t < o) s[t] += s[t + o];
        __syncthreads();
    }
    if (t == 0) bsum[blockIdx.x] = s[0];
}

__global__ void scan_top_kernel(int* __restrict__ bsum, int nb) {
    __shared__ int s[256];
    int t = threadIdx.x;
    int v = (t < nb) ? bsum[t] : 0;
    s[t] = v;
    __syncthreads();
    for (int o = 1; o < 256; o <<= 1) {
        int add = (t >= o) ? s[t - o] : 0;
        __syncthreads();
        s[t] += add;
        __syncthreads();
    }
    if (t < nb) bsum[t] = s[t] - v;
}

__global__ void scan_write_kernel(const int* __restrict__ cnt, const int* __restrict__ bsum,
                                  int* __restrict__ off, int n) {
    __shared__ int s[256];
    int base = blockIdx.x * 1024;
    int t = threadIdx.x;
    int v[4];
    int sum = 0;
#pragma unroll
    for (int i = 0; i < 4; ++i) {
        int idx = base + t * 4 + i;
        v[i] = (idx < n) ? cnt[idx] : 0;
        sum += v[i];
    }
    s[t] = sum;
    __syncthreads();
    for (int o = 1; o < 256; o <<= 1) {
        int add = (t >= o) ? s[t - o] : 0;
        __syncthreads();
        s[t] += add;
        __syncthreads();
    }
    int p = bsum[blockIdx.x] + s[t] - sum;
#pragma unroll
    for (int i = 0; i < 4; ++i) {
        int idx = base + t * 4 + i;
        if (idx < n) { off[idx] = p; p += v[i]; }
    }
}

// ---------------- atomic-free scatter: rows grouped by target ----------------
__global__ void scatter2_kernel(const int* __restrict__ rows, const int* __restrict__ cols,
                                const int* __restrict__ rank, const unsigned short* __restrict__ ph_col,
                                const int* __restrict__ off, int* __restrict__ rows_buf,
                                int E, int n, int log_epb) {
    int base = blockIdx.x * 1024 + threadIdx.x;
#pragma unroll
    for (int u = 0; u < 4; ++u) {
        int e = base + u * 256;
        if (e < E) {
            int k = cols[e];
            int b = e >> log_epb;
            int pos = off[k] + (int)ph_col[(size_t)b * n + k] + rank[e];
            rows_buf[pos] = rows[e];
        }
    }
}

// ---------------- linear via MFMA, plain bf16, output x16 (bf16) ----------------
// x16 = bf16(feat_bf16 @ W_bf16^T + b), fp32 MFMA accumulation.
// LDS: W pre-packed as B-fragments wb[ct][kq][lane][8]; layout verified on HW (R9 run).
__launch_bounds__(256)
__global__ void gemm_bf16_kernel(const float* __restrict__ feat, const float* __restrict__ W,
                                 const float* __restrict__ b, unsigned short* __restrict__ x16, int n) {
    __shared__ short wb[16384];  // 8ct * 4kq * 64lane * 8 bf16 = 32 KB

    const int t = threadIdx.x;

    // ---- convert W into pre-packed B-fragments ----
    {
        int c = t >> 1;                 // output channel (Wt col)
        int kbase = (t & 1) * 64;
        int ct = c >> 4;
        int cl = c & 15;
#pragma unroll
        for (int kc = 0; kc < 8; ++kc) {
            int k0 = kbase + kc * 8;
            const float4* src = (const float4*)(W + (size_t)c * NFEAT + k0);
            float4 fa = src[0];
            float4 fb = src[1];
            float fv[8] = {fa.x, fa.y, fa.z, fa.w, fb.x, fb.y, fb.z, fb.w};
            short h8[8];
#pragma unroll
            for (int i = 0; i < 8; ++i) h8[i] = f2bf(fv[i]);
            int kq = k0 >> 5;
            int lane = ((k0 & 31) >> 3) * 16 + cl;
            int idx = ((ct * 4 + kq) * 64 + lane) * 8;
            *(bf16x8*)&wb[idx] = *(bf16x8*)h8;
        }
    }
    __syncthreads();

    // ---- per-wave 16-row stripe ----
    const int lane = t & 63;
    const int w = t >> 6;
    const int r0 = blockIdx.x * 64 + w * 16;
    const int arow = r0 + (lane & 15);
    const int koff = (lane >> 4) * 8;

    bf16x8 a[4];
#pragma unroll
    for (int kq = 0; kq < 4; ++kq) {
        float fv[8] = {0, 0, 0, 0, 0, 0, 0, 0};
        if (arow < n) {
            const float4* src = (const float4*)(feat + (size_t)arow * NFEAT + kq * 32 + koff);
            float4 fa = src[0];
            float4 fb = src[1];
            fv[0] = fa.x; fv[1] = fa.y; fv[2] = fa.z; fv[3] = fa.w;
            fv[4] = fb.x; fv[5] = fb.y; fv[6] = fb.z; fv[7] = fb.w;
        }
        short h8[8];
#pragma unroll
        for (int i = 0; i < 8; ++i) h8[i] = f2bf(fv[i]);
        a[kq] = *(bf16x8*)h8;
    }

#pragma unroll
    for (int ct = 0; ct < 8; ++ct) {
        f32x4 acc = {0.f, 0.f, 0.f, 0.f};
#pragma unroll
        for (int kq = 0; kq < 4; ++kq) {
            int idx = ((ct * 4 + kq) * 64 + lane) * 8;
            bf16x8 bh = *(const bf16x8*)&wb[idx];
            acc = __builtin_amdgcn_mfma_f32_16x16x32_bf16(a[kq], bh, acc, 0, 0, 0);
        }
        int col = ct * 16 + (lane & 15);
        float bb = b[col];
#pragma unroll
        for (int reg = 0; reg < 4; ++reg) {
            int row = r0 + (lane >> 4) * 4 + reg;
            if (row < n) x16[(size_t)row * NFEAT + col] = (unsigned short)f2bf(acc[reg] + bb);
        }
    }
}

// ---------------- gather: bf16 rows, 4 edges/iter (quarter-waves), shfl broadcast ----------------
__launch_bounds__(256)
__global__ void gather_kernel(const int* __restrict__ rows_buf, const int* __restrict__ off,
                              const int* __restrict__ cnt, const unsigned short* __restrict__ x16,
                              const float* __restrict__ dis, float* __restrict__ out, int n) {
    int lane = threadIdx.x & 63;
    int q = lane >> 4;        // quarter id: processes edge 4j+q
    int fq = lane & 15;       // 8-feature chunk index
    int c = blockIdx.x * 4 + (threadIdx.x >> 6);
    if (c >= n) return;

    float disc = dis[c];
    int start = off[c];
    int len = cnt[c];
    const uint4* xv = (const uint4*)x16;  // row = 16 uint4 (128 bf16)

    float a0 = 0.f, a1 = 0.f, a2 = 0.f, a3 = 0.f, a4 = 0.f, a5 = 0.f, a6 = 0.f, a7 = 0.f;

    for (int base = 0; base < len; base += 64) {
        int m = min(64, len - base);
        int r_l = 0;
        float nrm_l = 0.0f;
        if (lane < m) {
            r_l = rows_buf[start + base + lane];
            nrm_l = dis[r_l] * disc;
        }
        int quads = (m + 3) >> 2;
#pragma unroll 4
        for (int jj = 0; jj < quads; ++jj) {
            int src = 4 * jj + q;
            int r = __shfl(r_l, src);
            float nm = __shfl(nrm_l, src);
            if (src < m) {   // quarter-uniform predicate
                uint4 v = xv[(size_t)r * 16 + fq];
                a0 = fmaf(bflo(v.x), nm, a0); a1 = fmaf(bfhi(v.x), nm, a1);
                a2 = fmaf(bflo(v.y), nm, a2); a3 = fmaf(bfhi(v.y), nm, a3);
                a4 = fmaf(bflo(v.z), nm, a4); a5 = fmaf(bfhi(v.z), nm, a5);
                a6 = fmaf(bflo(v.w), nm, a6); a7 = fmaf(bfhi(v.w), nm, a7);
            }
        }
    }

    // reduce across the 4 quarters (each quarter covered all features for its edges)
    a0 += __shfl_xor(a0, 16); a1 += __shfl_xor(a1, 16);
    a2 += __shfl_xor(a2, 16); a3 += __shfl_xor(a3, 16);
    a4 += __shfl_xor(a4, 16); a5 += __shfl_xor(a5, 16);
    a6 += __shfl_xor(a6, 16); a7 += __shfl_xor(a7, 16);
    a0 += __shfl_xor(a0, 32); a1 += __shfl_xor(a1, 32);
    a2 += __shfl_xor(a2, 32); a3 += __shfl_xor(a3, 32);
    a4 += __shfl_xor(a4, 32); a5 += __shfl_xor(a5, 32);
    a6 += __shfl_xor(a6, 32); a7 += __shfl_xor(a7, 32);

    if (q == 0) {
        // self-loop term
        float sl = disc * disc;
        uint4 v = xv[(size_t)c * 16 + fq];
        a0 = fmaf(bflo(v.x), sl, a0); a1 = fmaf(bfhi(v.x), sl, a1);
        a2 = fmaf(bflo(v.y), sl, a2); a3 = fmaf(bfhi(v.y), sl, a3);
        a4 = fmaf(bflo(v.z), sl, a4); a5 = fmaf(bfhi(v.z), sl, a5);
        a6 = fmaf(bflo(v.w), sl, a6); a7 = fmaf(bfhi(v.w), sl, a7);
        float4* o = (float4*)(out + (size_t)c * NFEAT + fq * 8);
        o[0] = make_float4(a0, a1, a2, a3);
        o[1] = make_float4(a4, a5, a6, a7);
    }
}

extern "C" void kernel_launch(void* const* d_in, const int* in_sizes, int n_in,
                              void* d_out, int out_size, void* d_ws, size_t ws_size,
                              hipStream_t stream) {
    const float* feat = (const float*)d_in[0];
    const int*   edges = (const int*)d_in[1];
    const float* W = (const float*)d_in[2];
    const float* b = (const float*)d_in[3];
    float* out = (float*)d_out;

    int n = in_sizes[0] / NFEAT;   // 100000
    int E = in_sizes[1] / 2;       // 1600000
    const int* row = edges;        // edges[0] = source
    const int* col = edges + E;    // edges[1] = target

    int Wd = (n + 1) / 2;
    int nchunk = (n + CH - 1) / CH;

    // fixed workspace (4B words): x16 (n*64) | dis n | colcnt n | off n | rows_buf E | rank E | bsum 256
    size_t fixed = (size_t)n * 64 + 3 * (size_t)n + 2 * (size_t)E + 256;
    int log_epb = 16;
    int NB = (E + (1 << 16) - 1) >> 16;
    for (int lg = 14; lg <= 16; ++lg) {
        int nb_try = (E + (1 << lg) - 1) >> lg;
        size_t words = fixed + 2 * (size_t)nb_try * Wd;
        if (words * 4 <= ws_size) { log_epb = lg; NB = nb_try; break; }
    }

    unsigned short* x16 = (unsigned short*)d_ws;           // n*128 bf16
    float* dis      = (float*)(x16 + (size_t)n * NFEAT);   // n
    int*   colcnt   = (int*)(dis + n);                     // n
    int*   off      = colcnt + n;                          // n
    int*   rows_buf = off + n;                             // E
    int*   rank     = rows_buf + E;                        // E
    int*   bsum     = rank + E;                            // 256
    unsigned int* ph_row = (unsigned int*)(bsum + 256);    // NB*Wd words
    unsigned int* ph_col = ph_row + (size_t)NB * Wd;       // NB*Wd words

    int nb = (n + 1023) / 1024;

    dim3 hgrid(NB, nchunk, 2);
    hist16_kernel<<<hgrid, 256, 0, stream>>>(row, col, ph_row, ph_col, rank, E, n, Wd, log_epb);

    cum_kernel<<<(n + 255) / 256, 256, 0, stream>>>((const unsigned short*)ph_row,
                                                    (unsigned short*)ph_col, dis, colcnt, NB, n);

    scan_bsum_kernel<<<nb, 256, 0, stream>>>(colcnt, bsum, n);
    scan_top_kernel<<<1, 256, 0, stream>>>(bsum, nb);
    scan_write_kernel<<<nb, 256, 0, stream>>>(colcnt, bsum, off, n);

    scatter2_kernel<<<(E + 1023) / 1024, 256, 0, stream>>>(row, col, rank,
                                                           (const unsigned short*)ph_col,
                                                           off, rows_buf, E, n, log_epb);

    gemm_bf16_kernel<<<(n + 63) / 64, 256, 0, stream>>>(feat, W, b, x16, n);

    gather_kernel<<<(n + 3) / 4, 256, 0, stream>>>(rows_buf, off, colcnt, x16, dis, out, n);
}